// Round 11
// baseline (476.672 us; speedup 1.0000x reference)
//
#include <hip/hip_runtime.h>
#include <hip/hip_fp16.h>

#define NODES 100000
#define NBKT 782            // ceil(100000/128) buckets of 128 cols
#define HCHUNK 8192         // edges per bucket_hist block
#define FCHUNK 4096         // edges per bucket_fill block (256 thr x 16)

typedef unsigned short u16;
typedef unsigned int u32;

__device__ __forceinline__ u16 f2bf(float f) {  // RNE (unused for tables now, kept for reference)
  u32 x = __float_as_uint(f);
  return (u16)((x + 0x7FFFu + ((x >> 16) & 1u)) >> 16);
}
__device__ __forceinline__ __half2 asH2(u32 v) {
  union { u32 u; __half2 h; } c; c.u = v; return c.h;
}

// ---------------- small utils ----------------

__global__ __launch_bounds__(256) void zero_k(int* __restrict__ p, int n) {
  int i = blockIdx.x * 256 + threadIdx.x;
  if (i < n) p[i] = 0;
}

// ---------------- bucket build ----------------

__global__ __launch_bounds__(256) void bucket_hist_k(const int* __restrict__ col,
                                                     int* __restrict__ bcnt, int E) {
  __shared__ int h[NBKT];
  int t = threadIdx.x;
  for (int i = t; i < NBKT; i += 256) h[i] = 0;
  __syncthreads();
  int base = blockIdx.x * HCHUNK;
#pragma unroll 4
  for (int j = 0; j < HCHUNK / 256; ++j) {
    int i = base + j * 256 + t;
    if (i < E) atomicAdd(&h[col[i] >> 7], 1);
  }
  __syncthreads();
  for (int i = t; i < NBKT; i += 256) {
    int c = h[i];
    if (c) atomicAdd(&bcnt[i], c);
  }
}

__global__ __launch_bounds__(256) void bscan_k(const int* __restrict__ bcnt,
                                               int* __restrict__ boffs,
                                               int* __restrict__ bcurs, int nb, int E) {
  __shared__ int lds[256];
  int t = threadIdx.x;
  int base = t * 4;
  int v[4];
#pragma unroll
  for (int j = 0; j < 4; ++j) v[j] = (base + j < nb) ? bcnt[base + j] : 0;
  int s = v[0] + v[1] + v[2] + v[3];
  lds[t] = s;
  __syncthreads();
  for (int off = 1; off < 256; off <<= 1) {
    int y = (t >= off) ? lds[t - off] : 0;
    __syncthreads();
    lds[t] += y;
    __syncthreads();
  }
  int excl = lds[t] - s;
#pragma unroll
  for (int j = 0; j < 4; ++j) {
    int i = base + j;
    if (i < nb) { boffs[i] = excl; bcurs[i] = excl; }
    excl += v[j];
  }
  if (t == 255) boffs[nb] = E;
}

// scatter packed records (colLow<<17 | row) into bucket regions.
__global__ __launch_bounds__(256) void bucket_fill_k(const int* __restrict__ row,
                                                     const int* __restrict__ col,
                                                     int* __restrict__ bcurs,
                                                     u32* __restrict__ recs, int E) {
  __shared__ int lcnt[NBKT];
  __shared__ int lbase[NBKT];
  int t = threadIdx.x;
  int base = blockIdx.x * FCHUNK;
  for (int i = t; i < NBKT; i += 256) lcnt[i] = 0;
  __syncthreads();
  u32 rec[FCHUNK / 256];
  u32 meta[FCHUNK / 256];
#pragma unroll
  for (int j = 0; j < FCHUNK / 256; ++j) {
    int i = base + j * 256 + t;
    if (i < E) {
      int r = row[i], c = col[i];
      int b = c >> 7;
      rec[j] = (u32)r | ((u32)(c & 127) << 17);
      int lr = atomicAdd(&lcnt[b], 1);
      meta[j] = (u32)lr | ((u32)b << 16);
    } else {
      meta[j] = 0xFFFFFFFFu;
    }
  }
  __syncthreads();
  for (int i = t; i < NBKT; i += 256) {
    int c = lcnt[i];
    lbase[i] = c ? atomicAdd(&bcurs[i], c) : 0;
  }
  __syncthreads();
#pragma unroll
  for (int j = 0; j < FCHUNK / 256; ++j) {
    if (meta[j] != 0xFFFFFFFFu) {
      int b = meta[j] >> 16;
      int lr = meta[j] & 0xFFFF;
      recs[lbase[b] + lr] = rec[j];
    }
  }
}

// records (bucketed by col) -> per-node CSR (offs, adj) + dis. One block per bucket.
__global__ __launch_bounds__(256) void csr_k(const u32* __restrict__ recs,
                                             const int* __restrict__ boffs,
                                             int* __restrict__ offs, int* __restrict__ adj,
                                             float* __restrict__ dis, int N, int E) {
  __shared__ int cnt[128];
  __shared__ int sa[128], sb[128];
  __shared__ int cur[128];
  int b = blockIdx.x, t = threadIdx.x;
  if (t < 128) cnt[t] = 0;
  __syncthreads();
  int s = boffs[b], e = boffs[b + 1];
  for (int i = s + t; i < e; i += 256) atomicAdd(&cnt[recs[i] >> 17], 1);
  __syncthreads();
  if (t < 128) sa[t] = cnt[t];
  __syncthreads();
#pragma unroll
  for (int off = 1; off < 128; off <<= 1) {
    if (t < 128) sb[t] = sa[t] + ((t >= off) ? sa[t - off] : 0);
    __syncthreads();
    if (t < 128) sa[t] = sb[t];
    __syncthreads();
  }
  if (t < 128) {
    int c = b * 128 + t;
    if (c < N) {
      int excl = sa[t] - cnt[t];
      offs[c] = s + excl;
      cur[t] = s + excl;
      dis[c] = rsqrtf((float)(cnt[t] + 1));  // +1 self loop
    }
  }
  if (b == 0 && t == 0) offs[N] = E;
  __syncthreads();
  for (int i = s + t; i < e; i += 256) {
    u32 r = recs[i];
    int p = atomicAdd(&cur[r >> 17], 1);
    adj[p] = (int)(r & 0x1FFFF);
  }
}

// ---------------- GEMM (NOUT=64): G[node,:] = (X[node,:] @ W) * dis[node], fp16 out ----------------
template <int K, int NK>
__global__ __launch_bounds__(256, 2) void gemm64_k(const float* __restrict__ X,
                                                   const float* __restrict__ W,
                                                   const float* __restrict__ dis,
                                                   u16* __restrict__ G, int n) {
  static_assert(K == NK * 4, "NT=4");
  __shared__ float ws[K * 64];
  int t = threadIdx.x;
  for (int i = t; i < K * 64; i += 256) ws[i] = W[i];
  __syncthreads();
  int q = t & 3, g = t >> 2;
  int b0 = blockIdx.x * 128;
  int n0 = b0 + g, n1 = b0 + 64 + g;
  int c0 = (n0 < n) ? n0 : 0, c1 = (n1 < n) ? n1 : 0;
  float xv0[NK], xv1[NK];
  const float* p0 = X + (size_t)c0 * K + q * NK;
  const float* p1 = X + (size_t)c1 * K + q * NK;
  if constexpr (NK % 4 == 0) {
#pragma unroll
    for (int i = 0; i < NK / 4; ++i) {
      *(float4*)&xv0[4 * i] = *(const float4*)(p0 + 4 * i);
      *(float4*)&xv1[4 * i] = *(const float4*)(p1 + 4 * i);
    }
  } else {
#pragma unroll
    for (int i = 0; i < NK; ++i) { xv0[i] = p0[i]; xv1[i] = p1[i]; }
  }
  float acc0[16], acc1[16];
#pragma unroll
  for (int j = 0; j < 16; ++j) { acc0[j] = 0.f; acc1[j] = 0.f; }
  for (int qq = 0; qq < 4; ++qq) {
    const float* wbase = ws + (size_t)qq * NK * 64 + q * 16;
#pragma unroll
    for (int i = 0; i < NK; ++i) {
      float a0 = __shfl(xv0[i], qq, 4);
      float a1 = __shfl(xv1[i], qq, 4);
      const float* wr = wbase + i * 64;
#pragma unroll
      for (int j = 0; j < 16; ++j) {
        float w = wr[j];
        acc0[j] = fmaf(a0, w, acc0[j]);
        acc1[j] = fmaf(a1, w, acc1[j]);
      }
    }
  }
  uint4* G4 = (uint4*)G;
  {
    if (n0 < n) {
      float sc = dis[n0];
      u32 os[8];
#pragma unroll
      for (int j = 0; j < 8; ++j) {
        u16 lo = __half_as_ushort(__float2half(acc0[2 * j] * sc));
        u16 hi = __half_as_ushort(__float2half(acc0[2 * j + 1] * sc));
        os[j] = (u32)lo | ((u32)hi << 16);
      }
      size_t rb = (size_t)n0 * 8 + q * 2;
      G4[rb]     = make_uint4(os[0], os[1], os[2], os[3]);
      G4[rb + 1] = make_uint4(os[4], os[5], os[6], os[7]);
    }
    if (n1 < n) {
      float sc = dis[n1];
      u32 os[8];
#pragma unroll
      for (int j = 0; j < 8; ++j) {
        u16 lo = __half_as_ushort(__float2half(acc1[2 * j] * sc));
        u16 hi = __half_as_ushort(__float2half(acc1[2 * j + 1] * sc));
        os[j] = (u32)lo | ((u32)hi << 16);
      }
      size_t rb = (size_t)n1 * 8 + q * 2;
      G4[rb]     = make_uint4(os[0], os[1], os[2], os[3]);
      G4[rb + 1] = make_uint4(os[4], os[5], os[6], os[7]);
    }
  }
}

// ---------------- GEMM (final, NOUT=18, fp16 out): 2 threads/node, outs split 10/8 ----------------
__global__ __launch_bounds__(256, 2) void gemm18_k(const float* __restrict__ X,  // K=64
                                                   const float* __restrict__ W,
                                                   const float* __restrict__ dis,
                                                   u16* __restrict__ G, int n) {
  __shared__ float ws[64 * 18];
  int t = threadIdx.x;
  for (int i = t; i < 64 * 18; i += 256) ws[i] = W[i];
  __syncthreads();
  int q = t & 1, g = t >> 1;
  int b0 = blockIdx.x * 128;
  int node = b0 + g;
  int cn = (node < n) ? node : 0;
  float xv[32];
  const float* p = X + (size_t)cn * 64 + q * 32;
#pragma unroll
  for (int i = 0; i < 8; ++i) *(float4*)&xv[4 * i] = *(const float4*)(p + 4 * i);
  int cnt = q ? 8 : 10;
  float acc[10];
#pragma unroll
  for (int j = 0; j < 10; ++j) acc[j] = 0.f;
  for (int qq = 0; qq < 2; ++qq) {
    const float* wbase = ws + (size_t)qq * 32 * 18 + q * 10;
#pragma unroll
    for (int i = 0; i < 32; ++i) {
      float a = __shfl(xv[i], qq, 2);
      const float* wr = wbase + i * 18;
#pragma unroll
      for (int j = 0; j < 10; ++j)
        if (j < cnt) acc[j] = fmaf(a, wr[j], acc[j]);
    }
  }
  if (node >= n) return;
  float sc = dis[node];
  u32* G32 = (u32*)G;
  if (q == 0) {
    u32 os[5];
#pragma unroll
    for (int j = 0; j < 5; ++j) {
      u16 lo = __half_as_ushort(__float2half(acc[2 * j] * sc));
      u16 hi = __half_as_ushort(__float2half(acc[2 * j + 1] * sc));
      os[j] = (u32)lo | ((u32)hi << 16);
    }
#pragma unroll
    for (int j = 0; j < 5; ++j) G32[(size_t)node * 9 + j] = os[j];
  } else {
    u32 os[4];
#pragma unroll
    for (int j = 0; j < 4; ++j) {
      u16 lo = __half_as_ushort(__float2half(acc[2 * j] * sc));
      u16 hi = __half_as_ushort(__float2half(acc[2 * j + 1] * sc));
      os[j] = (u32)lo | ((u32)hi << 16);
    }
#pragma unroll
    for (int j = 0; j < 4; ++j) G32[(size_t)node * 9 + 5 + j] = os[j];
  }
}

// ---------------- aggregation (hidden, fp16 table): 2 edges per wave-gather, 16 in flight ----------------
// R6 memory structure (half-split, best measured) + packed-half2 tree accumulation:
// 8 u32 (=half2) reduce via 7 v_pk_add_f16, then 1 cvt + 2 fp32 adds per 16-edge group.
__global__ __launch_bounds__(256) void agg_f16_k(const u16* __restrict__ g,
                                                 const int* __restrict__ offs,
                                                 const int* __restrict__ adj,
                                                 const float* __restrict__ dis,
                                                 const float* __restrict__ bias,
                                                 float* __restrict__ out, int n) {
  int node = blockIdx.x * 4 + (threadIdx.x >> 6);
  int lane = threadIdx.x & 63;
  int half = lane >> 5, fl = lane & 31;
  if (node >= n) return;
  const u32* g32 = (const u32*)g;
  float acc0 = 0.f, acc1 = 0.f;
  int s = offs[node], e = offs[node + 1];
  int i = s;
  for (; i + 16 <= e; i += 16) {  // 8 gathers in flight per lane
    int r0 = adj[i + half];
    int r1 = adj[i + 2 + half];
    int r2 = adj[i + 4 + half];
    int r3 = adj[i + 6 + half];
    int r4 = adj[i + 8 + half];
    int r5 = adj[i + 10 + half];
    int r6 = adj[i + 12 + half];
    int r7 = adj[i + 14 + half];
    u32 v0 = g32[(r0 << 5) + fl];
    u32 v1 = g32[(r1 << 5) + fl];
    u32 v2 = g32[(r2 << 5) + fl];
    u32 v3 = g32[(r3 << 5) + fl];
    u32 v4 = g32[(r4 << 5) + fl];
    u32 v5 = g32[(r5 << 5) + fl];
    u32 v6 = g32[(r6 << 5) + fl];
    u32 v7 = g32[(r7 << 5) + fl];
    __half2 s01 = __hadd2(asH2(v0), asH2(v1));
    __half2 s23 = __hadd2(asH2(v2), asH2(v3));
    __half2 s45 = __hadd2(asH2(v4), asH2(v5));
    __half2 s67 = __hadd2(asH2(v6), asH2(v7));
    __half2 sA = __hadd2(s01, s23);
    __half2 sB = __hadd2(s45, s67);
    float2 f = __half22float2(__hadd2(sA, sB));
    acc0 += f.x;
    acc1 += f.y;
  }
  for (; i + 2 <= e; i += 2) {
    int r = adj[i + half];
    float2 f = __half22float2(asH2(g32[(r << 5) + fl]));
    acc0 += f.x;
    acc1 += f.y;
  }
  if (i < e) {  // odd tail edge: only half 0 counts it
    int r = adj[i];
    float2 f = __half22float2(asH2(g32[(r << 5) + fl]));
    if (half == 0) { acc0 += f.x; acc1 += f.y; }
  }
  acc0 += __shfl_xor(acc0, 32, 64);
  acc1 += __shfl_xor(acc1, 32, 64);
  float2 fs = __half22float2(asH2(g32[(node << 5) + fl]));  // self loop (pre-scaled)
  acc0 += fs.x;
  acc1 += fs.y;
  float d = dis[node];
  float o0 = fmaxf(fmaf(d, acc0, bias[2 * fl]), 0.f);
  float o1 = fmaxf(fmaf(d, acc1, bias[2 * fl + 1]), 0.f);
  if (half == 0) {
    float2 st = {o0, o1};
    *(float2*)(out + node * 64 + 2 * fl) = st;
  }
}

// ---------------- aggregation (final, 18-wide fp16 table): 2 edges/gather, 16 in flight ----------------
__global__ __launch_bounds__(256) void agg_f16o_k(const u16* __restrict__ g,
                                                  const int* __restrict__ offs,
                                                  const int* __restrict__ adj,
                                                  const float* __restrict__ dis,
                                                  const float* __restrict__ bias,
                                                  float* __restrict__ out, int n) {
  int node = blockIdx.x * 4 + (threadIdx.x >> 6);
  int lane = threadIdx.x & 63;
  int half = lane >> 5, fl = lane & 31;
  if (node >= n) return;
  const __half* gh = (const __half*)g;
  bool act = fl < 18;
  float acc = 0.f;
  int s = offs[node], e = offs[node + 1];
  int i = s;
  if (act) {
    for (; i + 16 <= e; i += 16) {
      int r0 = adj[i + half];
      int r1 = adj[i + 2 + half];
      int r2 = adj[i + 4 + half];
      int r3 = adj[i + 6 + half];
      int r4 = adj[i + 8 + half];
      int r5 = adj[i + 10 + half];
      int r6 = adj[i + 12 + half];
      int r7 = adj[i + 14 + half];
      float a0 = __half2float(gh[r0 * 18 + fl]);
      float a1 = __half2float(gh[r1 * 18 + fl]);
      float a2 = __half2float(gh[r2 * 18 + fl]);
      float a3 = __half2float(gh[r3 * 18 + fl]);
      float a4 = __half2float(gh[r4 * 18 + fl]);
      float a5 = __half2float(gh[r5 * 18 + fl]);
      float a6 = __half2float(gh[r6 * 18 + fl]);
      float a7 = __half2float(gh[r7 * 18 + fl]);
      acc += ((a0 + a1) + (a2 + a3)) + ((a4 + a5) + (a6 + a7));
    }
    for (; i + 8 <= e; i += 8) {
      int r0 = adj[i + half];
      int r1 = adj[i + 2 + half];
      int r2 = adj[i + 4 + half];
      int r3 = adj[i + 6 + half];
      float a0 = __half2float(gh[r0 * 18 + fl]);
      float a1 = __half2float(gh[r1 * 18 + fl]);
      float a2 = __half2float(gh[r2 * 18 + fl]);
      float a3 = __half2float(gh[r3 * 18 + fl]);
      acc += (a0 + a1) + (a2 + a3);
    }
    for (; i + 2 <= e; i += 2) acc += __half2float(gh[adj[i + half] * 18 + fl]);
    if (i < e && half == 0) acc += __half2float(gh[adj[i] * 18 + fl]);
  }
  acc += __shfl_xor(acc, 32, 64);  // all 64 lanes participate
  if (act) {
    acc += __half2float(gh[node * 18 + fl]);  // self loop
    float v = fmaf(dis[node], acc, bias[fl]);
    if (half == 0) out[node * 18 + fl] = v;
  }
}

// ---------------- launch ----------------

extern "C" void kernel_launch(void* const* d_in, const int* in_sizes, int n_in,
                              void* d_out, int out_size, void* d_ws, size_t ws_size,
                              hipStream_t stream) {
  const float* x  = (const float*)d_in[0];
  const int*   ei = (const int*)d_in[1];
  const float* W1 = (const float*)d_in[2];
  const float* b1 = (const float*)d_in[3];
  const float* W2 = (const float*)d_in[4];
  const float* b2 = (const float*)d_in[5];
  const float* W3 = (const float*)d_in[6];
  const float* b3 = (const float*)d_in[7];
  const float* Wo = (const float*)d_in[8];
  const float* bo = (const float*)d_in[9];
  float* out = (float*)d_out;

  const int N = NODES;
  const int E = in_sizes[1] / 2;
  const int* rowp = ei;
  const int* colp = ei + E;

  char* p = (char*)d_ws;
  auto alloc = [&](size_t bytes) {
    void* r = (void*)p;
    p += (bytes + 255) & ~(size_t)255;
    return r;
  };
  int*   bcnt  = (int*)alloc((size_t)NBKT * 4);
  int*   bcurs = (int*)alloc((size_t)NBKT * 4);
  int*   boffs = (int*)alloc((size_t)(NBKT + 1) * 4);
  float* dis   = (float*)alloc((size_t)N * 4);
  int*   offs  = (int*)alloc((size_t)(N + 1) * 4);
  int*   adj   = (int*)alloc((size_t)E * 4);
  // recs (E*4 = 12.8MB) dead after csr_k; alias with fp16 gather table (N*64*2 = 12.8MB)
  u32*   recs  = (u32*)alloc((size_t)N * 64 * 2);
  u16*   gb    = (u16*)recs;
  float* h     = (float*)alloc((size_t)N * 64 * 4);   // fp32 hidden activations
  u16*   g4    = (u16*)alloc((size_t)N * 18 * 2);    // fp16 gather table, final layer

  zero_k<<<(NBKT + 255) / 256, 256, 0, stream>>>(bcnt, NBKT);
  bucket_hist_k<<<(E + HCHUNK - 1) / HCHUNK, 256, 0, stream>>>(colp, bcnt, E);
  bscan_k<<<1, 256, 0, stream>>>(bcnt, boffs, bcurs, NBKT, E);
  bucket_fill_k<<<(E + FCHUNK - 1) / FCHUNK, 256, 0, stream>>>(rowp, colp, bcurs, recs, E);
  csr_k<<<NBKT, 256, 0, stream>>>(recs, boffs, offs, adj, dis, N, E);

  int gG = (N + 127) / 128;   // 128 nodes per gemm block
  int gA = (N + 3) / 4;

  gemm64_k<100, 25><<<gG, 256, 0, stream>>>(x, W1, dis, gb, N);
  agg_f16_k<<<gA, 256, 0, stream>>>(gb, offs, adj, dis, b1, h, N);

  gemm64_k<64, 16><<<gG, 256, 0, stream>>>(h, W2, dis, gb, N);
  agg_f16_k<<<gA, 256, 0, stream>>>(gb, offs, adj, dis, b2, h, N);

  gemm64_k<64, 16><<<gG, 256, 0, stream>>>(h, W3, dis, gb, N);
  agg_f16_k<<<gA, 256, 0, stream>>>(gb, offs, adj, dis, b3, h, N);

  gemm18_k<<<gG, 256, 0, stream>>>(h, Wo, dis, g4, N);
  agg_f16o_k<<<gA, 256, 0, stream>>>(g4, offs, adj, dis, bo, out, N);
}

// Round 12
// 426.273 us; speedup vs baseline: 1.1182x; 1.1182x over previous
//
#include <hip/hip_runtime.h>
#include <hip/hip_fp16.h>

#define NODES 100000
#define NBKT 782            // ceil(100000/128) buckets of 128 cols
#define HCHUNK 8192         // edges per bucket_hist block
#define FCHUNK 4096         // edges per bucket_fill block (256 thr x 16)

typedef unsigned short u16;
typedef unsigned int u32;

__device__ __forceinline__ __half2 asH2(u32 v) {
  union { u32 u; __half2 h; } c; c.u = v; return c.h;
}

// ---------------- small utils ----------------

__global__ __launch_bounds__(256) void zero_k(int* __restrict__ p, int n) {
  int i = blockIdx.x * 256 + threadIdx.x;
  if (i < n) p[i] = 0;
}

// ---------------- bucket build ----------------

__global__ __launch_bounds__(256) void bucket_hist_k(const int* __restrict__ col,
                                                     int* __restrict__ bcnt, int E) {
  __shared__ int h[NBKT];
  int t = threadIdx.x;
  for (int i = t; i < NBKT; i += 256) h[i] = 0;
  __syncthreads();
  int base = blockIdx.x * HCHUNK;
#pragma unroll 4
  for (int j = 0; j < HCHUNK / 256; ++j) {
    int i = base + j * 256 + t;
    if (i < E) atomicAdd(&h[col[i] >> 7], 1);
  }
  __syncthreads();
  for (int i = t; i < NBKT; i += 256) {
    int c = h[i];
    if (c) atomicAdd(&bcnt[i], c);
  }
}

__global__ __launch_bounds__(256) void bscan_k(const int* __restrict__ bcnt,
                                               int* __restrict__ boffs,
                                               int* __restrict__ bcurs, int nb, int E) {
  __shared__ int lds[256];
  int t = threadIdx.x;
  int base = t * 4;
  int v[4];
#pragma unroll
  for (int j = 0; j < 4; ++j) v[j] = (base + j < nb) ? bcnt[base + j] : 0;
  int s = v[0] + v[1] + v[2] + v[3];
  lds[t] = s;
  __syncthreads();
  for (int off = 1; off < 256; off <<= 1) {
    int y = (t >= off) ? lds[t - off] : 0;
    __syncthreads();
    lds[t] += y;
    __syncthreads();
  }
  int excl = lds[t] - s;
#pragma unroll
  for (int j = 0; j < 4; ++j) {
    int i = base + j;
    if (i < nb) { boffs[i] = excl; bcurs[i] = excl; }
    excl += v[j];
  }
  if (t == 255) boffs[nb] = E;
}

// scatter packed records (colLow<<17 | row) into bucket regions.
__global__ __launch_bounds__(256) void bucket_fill_k(const int* __restrict__ row,
                                                     const int* __restrict__ col,
                                                     int* __restrict__ bcurs,
                                                     u32* __restrict__ recs, int E) {
  __shared__ int lcnt[NBKT];
  __shared__ int lbase[NBKT];
  int t = threadIdx.x;
  int base = blockIdx.x * FCHUNK;
  for (int i = t; i < NBKT; i += 256) lcnt[i] = 0;
  __syncthreads();
  u32 rec[FCHUNK / 256];
  u32 meta[FCHUNK / 256];
#pragma unroll
  for (int j = 0; j < FCHUNK / 256; ++j) {
    int i = base + j * 256 + t;
    if (i < E) {
      int r = row[i], c = col[i];
      int b = c >> 7;
      rec[j] = (u32)r | ((u32)(c & 127) << 17);
      int lr = atomicAdd(&lcnt[b], 1);
      meta[j] = (u32)lr | ((u32)b << 16);
    } else {
      meta[j] = 0xFFFFFFFFu;
    }
  }
  __syncthreads();
  for (int i = t; i < NBKT; i += 256) {
    int c = lcnt[i];
    lbase[i] = c ? atomicAdd(&bcurs[i], c) : 0;
  }
  __syncthreads();
#pragma unroll
  for (int j = 0; j < FCHUNK / 256; ++j) {
    if (meta[j] != 0xFFFFFFFFu) {
      int b = meta[j] >> 16;
      int lr = meta[j] & 0xFFFF;
      recs[lbase[b] + lr] = rec[j];
    }
  }
}

// records (bucketed by col) -> per-node CSR (offs, adj) + dis. One block per bucket.
__global__ __launch_bounds__(256) void csr_k(const u32* __restrict__ recs,
                                             const int* __restrict__ boffs,
                                             int* __restrict__ offs, int* __restrict__ adj,
                                             float* __restrict__ dis, int N, int E) {
  __shared__ int cnt[128];
  __shared__ int sa[128], sb[128];
  __shared__ int cur[128];
  int b = blockIdx.x, t = threadIdx.x;
  if (t < 128) cnt[t] = 0;
  __syncthreads();
  int s = boffs[b], e = boffs[b + 1];
  for (int i = s + t; i < e; i += 256) atomicAdd(&cnt[recs[i] >> 17], 1);
  __syncthreads();
  if (t < 128) sa[t] = cnt[t];
  __syncthreads();
#pragma unroll
  for (int off = 1; off < 128; off <<= 1) {
    if (t < 128) sb[t] = sa[t] + ((t >= off) ? sa[t - off] : 0);
    __syncthreads();
    if (t < 128) sa[t] = sb[t];
    __syncthreads();
  }
  if (t < 128) {
    int c = b * 128 + t;
    if (c < N) {
      int excl = sa[t] - cnt[t];
      offs[c] = s + excl;
      cur[t] = s + excl;
      dis[c] = rsqrtf((float)(cnt[t] + 1));  // +1 self loop
    }
  }
  if (b == 0 && t == 0) offs[N] = E;
  __syncthreads();
  for (int i = s + t; i < e; i += 256) {
    u32 r = recs[i];
    int p = atomicAdd(&cur[r >> 17], 1);
    adj[p] = (int)(r & 0x1FFFF);
  }
}

// ---------------- GEMM (NOUT=64): G[node,:] = (X[node,:] @ W) * dis[node], fp16 out ----------------
template <int K, int NK>
__global__ __launch_bounds__(256, 2) void gemm64_k(const float* __restrict__ X,
                                                   const float* __restrict__ W,
                                                   const float* __restrict__ dis,
                                                   u16* __restrict__ G, int n) {
  static_assert(K == NK * 4, "NT=4");
  __shared__ float ws[K * 64];
  int t = threadIdx.x;
  for (int i = t; i < K * 64; i += 256) ws[i] = W[i];
  __syncthreads();
  int q = t & 3, g = t >> 2;
  int b0 = blockIdx.x * 128;
  int n0 = b0 + g, n1 = b0 + 64 + g;
  int c0 = (n0 < n) ? n0 : 0, c1 = (n1 < n) ? n1 : 0;
  float xv0[NK], xv1[NK];
  const float* p0 = X + (size_t)c0 * K + q * NK;
  const float* p1 = X + (size_t)c1 * K + q * NK;
  if constexpr (NK % 4 == 0) {
#pragma unroll
    for (int i = 0; i < NK / 4; ++i) {
      *(float4*)&xv0[4 * i] = *(const float4*)(p0 + 4 * i);
      *(float4*)&xv1[4 * i] = *(const float4*)(p1 + 4 * i);
    }
  } else {
#pragma unroll
    for (int i = 0; i < NK; ++i) { xv0[i] = p0[i]; xv1[i] = p1[i]; }
  }
  float acc0[16], acc1[16];
#pragma unroll
  for (int j = 0; j < 16; ++j) { acc0[j] = 0.f; acc1[j] = 0.f; }
  for (int qq = 0; qq < 4; ++qq) {
    const float* wbase = ws + (size_t)qq * NK * 64 + q * 16;
#pragma unroll
    for (int i = 0; i < NK; ++i) {
      float a0 = __shfl(xv0[i], qq, 4);
      float a1 = __shfl(xv1[i], qq, 4);
      const float* wr = wbase + i * 64;
#pragma unroll
      for (int j = 0; j < 16; ++j) {
        float w = wr[j];
        acc0[j] = fmaf(a0, w, acc0[j]);
        acc1[j] = fmaf(a1, w, acc1[j]);
      }
    }
  }
  uint4* G4 = (uint4*)G;
  {
    if (n0 < n) {
      float sc = dis[n0];
      u32 os[8];
#pragma unroll
      for (int j = 0; j < 8; ++j) {
        u16 lo = __half_as_ushort(__float2half(acc0[2 * j] * sc));
        u16 hi = __half_as_ushort(__float2half(acc0[2 * j + 1] * sc));
        os[j] = (u32)lo | ((u32)hi << 16);
      }
      size_t rb = (size_t)n0 * 8 + q * 2;
      G4[rb]     = make_uint4(os[0], os[1], os[2], os[3]);
      G4[rb + 1] = make_uint4(os[4], os[5], os[6], os[7]);
    }
    if (n1 < n) {
      float sc = dis[n1];
      u32 os[8];
#pragma unroll
      for (int j = 0; j < 8; ++j) {
        u16 lo = __half_as_ushort(__float2half(acc1[2 * j] * sc));
        u16 hi = __half_as_ushort(__float2half(acc1[2 * j + 1] * sc));
        os[j] = (u32)lo | ((u32)hi << 16);
      }
      size_t rb = (size_t)n1 * 8 + q * 2;
      G4[rb]     = make_uint4(os[0], os[1], os[2], os[3]);
      G4[rb + 1] = make_uint4(os[4], os[5], os[6], os[7]);
    }
  }
}

// ---------------- GEMM (final, NOUT=18, fp16 out): 2 threads/node, outs split 10/8 ----------------
__global__ __launch_bounds__(256, 2) void gemm18_k(const float* __restrict__ X,  // K=64
                                                   const float* __restrict__ W,
                                                   const float* __restrict__ dis,
                                                   u16* __restrict__ G, int n) {
  __shared__ float ws[64 * 18];
  int t = threadIdx.x;
  for (int i = t; i < 64 * 18; i += 256) ws[i] = W[i];
  __syncthreads();
  int q = t & 1, g = t >> 1;
  int b0 = blockIdx.x * 128;
  int node = b0 + g;
  int cn = (node < n) ? node : 0;
  float xv[32];
  const float* p = X + (size_t)cn * 64 + q * 32;
#pragma unroll
  for (int i = 0; i < 8; ++i) *(float4*)&xv[4 * i] = *(const float4*)(p + 4 * i);
  int cnt = q ? 8 : 10;
  float acc[10];
#pragma unroll
  for (int j = 0; j < 10; ++j) acc[j] = 0.f;
  for (int qq = 0; qq < 2; ++qq) {
    const float* wbase = ws + (size_t)qq * 32 * 18 + q * 10;
#pragma unroll
    for (int i = 0; i < 32; ++i) {
      float a = __shfl(xv[i], qq, 2);
      const float* wr = wbase + i * 18;
#pragma unroll
      for (int j = 0; j < 10; ++j)
        if (j < cnt) acc[j] = fmaf(a, wr[j], acc[j]);
    }
  }
  if (node >= n) return;
  float sc = dis[node];
  u32* G32 = (u32*)G;
  if (q == 0) {
    u32 os[5];
#pragma unroll
    for (int j = 0; j < 5; ++j) {
      u16 lo = __half_as_ushort(__float2half(acc[2 * j] * sc));
      u16 hi = __half_as_ushort(__float2half(acc[2 * j + 1] * sc));
      os[j] = (u32)lo | ((u32)hi << 16);
    }
#pragma unroll
    for (int j = 0; j < 5; ++j) G32[(size_t)node * 9 + j] = os[j];
  } else {
    u32 os[4];
#pragma unroll
    for (int j = 0; j < 4; ++j) {
      u16 lo = __half_as_ushort(__float2half(acc[2 * j] * sc));
      u16 hi = __half_as_ushort(__float2half(acc[2 * j + 1] * sc));
      os[j] = (u32)lo | ((u32)hi << 16);
    }
#pragma unroll
    for (int j = 0; j < 4; ++j) G32[(size_t)node * 9 + 5 + j] = os[j];
  }
}

// ---------------- aggregation (hidden, fp16 table): 2 edges/wave-gather ----------------
// Full MLP ladder restored: 16 (8 gathers in flight) -> 8 (4) -> 4 (2) -> 2 -> 1.
// Packed half2 tree adds in the wide rungs; fp32 accumulate across rungs.
__global__ __launch_bounds__(256) void agg_f16_k(const u16* __restrict__ g,
                                                 const int* __restrict__ offs,
                                                 const int* __restrict__ adj,
                                                 const float* __restrict__ dis,
                                                 const float* __restrict__ bias,
                                                 float* __restrict__ out, int n) {
  int node = blockIdx.x * 4 + (threadIdx.x >> 6);
  int lane = threadIdx.x & 63;
  int half = lane >> 5, fl = lane & 31;
  if (node >= n) return;
  const u32* g32 = (const u32*)g;
  float acc0 = 0.f, acc1 = 0.f;
  int s = offs[node], e = offs[node + 1];
  int i = s;
  for (; i + 16 <= e; i += 16) {  // 8 gathers in flight per lane
    int r0 = adj[i + half];
    int r1 = adj[i + 2 + half];
    int r2 = adj[i + 4 + half];
    int r3 = adj[i + 6 + half];
    int r4 = adj[i + 8 + half];
    int r5 = adj[i + 10 + half];
    int r6 = adj[i + 12 + half];
    int r7 = adj[i + 14 + half];
    u32 v0 = g32[(r0 << 5) + fl];
    u32 v1 = g32[(r1 << 5) + fl];
    u32 v2 = g32[(r2 << 5) + fl];
    u32 v3 = g32[(r3 << 5) + fl];
    u32 v4 = g32[(r4 << 5) + fl];
    u32 v5 = g32[(r5 << 5) + fl];
    u32 v6 = g32[(r6 << 5) + fl];
    u32 v7 = g32[(r7 << 5) + fl];
    __half2 sA = __hadd2(__hadd2(asH2(v0), asH2(v1)), __hadd2(asH2(v2), asH2(v3)));
    __half2 sB = __hadd2(__hadd2(asH2(v4), asH2(v5)), __hadd2(asH2(v6), asH2(v7)));
    float2 f = __half22float2(__hadd2(sA, sB));
    acc0 += f.x;
    acc1 += f.y;
  }
  if (i + 8 <= e) {  // 4 gathers in flight
    int r0 = adj[i + half];
    int r1 = adj[i + 2 + half];
    int r2 = adj[i + 4 + half];
    int r3 = adj[i + 6 + half];
    u32 v0 = g32[(r0 << 5) + fl];
    u32 v1 = g32[(r1 << 5) + fl];
    u32 v2 = g32[(r2 << 5) + fl];
    u32 v3 = g32[(r3 << 5) + fl];
    float2 f = __half22float2(__hadd2(__hadd2(asH2(v0), asH2(v1)),
                                      __hadd2(asH2(v2), asH2(v3))));
    acc0 += f.x;
    acc1 += f.y;
    i += 8;
  }
  if (i + 4 <= e) {  // 2 gathers in flight
    int r0 = adj[i + half];
    int r1 = adj[i + 2 + half];
    u32 v0 = g32[(r0 << 5) + fl];
    u32 v1 = g32[(r1 << 5) + fl];
    float2 f = __half22float2(__hadd2(asH2(v0), asH2(v1)));
    acc0 += f.x;
    acc1 += f.y;
    i += 4;
  }
  if (i + 2 <= e) {
    int r = adj[i + half];
    float2 f = __half22float2(asH2(g32[(r << 5) + fl]));
    acc0 += f.x;
    acc1 += f.y;
    i += 2;
  }
  if (i < e) {  // odd tail edge: only half 0 counts it
    int r = adj[i];
    float2 f = __half22float2(asH2(g32[(r << 5) + fl]));
    if (half == 0) { acc0 += f.x; acc1 += f.y; }
  }
  acc0 += __shfl_xor(acc0, 32, 64);
  acc1 += __shfl_xor(acc1, 32, 64);
  float2 fs = __half22float2(asH2(g32[(node << 5) + fl]));  // self loop (pre-scaled)
  acc0 += fs.x;
  acc1 += fs.y;
  float d = dis[node];
  float o0 = fmaxf(fmaf(d, acc0, bias[2 * fl]), 0.f);
  float o1 = fmaxf(fmaf(d, acc1, bias[2 * fl + 1]), 0.f);
  if (half == 0) {
    float2 st = {o0, o1};
    *(float2*)(out + node * 64 + 2 * fl) = st;
  }
}

// ---------------- aggregation (final, 18-wide fp16 table): 2 edges/gather, full ladder ----------------
__global__ __launch_bounds__(256) void agg_f16o_k(const u16* __restrict__ g,
                                                  const int* __restrict__ offs,
                                                  const int* __restrict__ adj,
                                                  const float* __restrict__ dis,
                                                  const float* __restrict__ bias,
                                                  float* __restrict__ out, int n) {
  int node = blockIdx.x * 4 + (threadIdx.x >> 6);
  int lane = threadIdx.x & 63;
  int half = lane >> 5, fl = lane & 31;
  if (node >= n) return;
  const __half* gh = (const __half*)g;
  bool act = fl < 18;
  float acc = 0.f;
  int s = offs[node], e = offs[node + 1];
  int i = s;
  if (act) {
    for (; i + 16 <= e; i += 16) {
      int r0 = adj[i + half];
      int r1 = adj[i + 2 + half];
      int r2 = adj[i + 4 + half];
      int r3 = adj[i + 6 + half];
      int r4 = adj[i + 8 + half];
      int r5 = adj[i + 10 + half];
      int r6 = adj[i + 12 + half];
      int r7 = adj[i + 14 + half];
      float a0 = __half2float(gh[r0 * 18 + fl]);
      float a1 = __half2float(gh[r1 * 18 + fl]);
      float a2 = __half2float(gh[r2 * 18 + fl]);
      float a3 = __half2float(gh[r3 * 18 + fl]);
      float a4 = __half2float(gh[r4 * 18 + fl]);
      float a5 = __half2float(gh[r5 * 18 + fl]);
      float a6 = __half2float(gh[r6 * 18 + fl]);
      float a7 = __half2float(gh[r7 * 18 + fl]);
      acc += ((a0 + a1) + (a2 + a3)) + ((a4 + a5) + (a6 + a7));
    }
    if (i + 8 <= e) {
      int r0 = adj[i + half];
      int r1 = adj[i + 2 + half];
      int r2 = adj[i + 4 + half];
      int r3 = adj[i + 6 + half];
      float a0 = __half2float(gh[r0 * 18 + fl]);
      float a1 = __half2float(gh[r1 * 18 + fl]);
      float a2 = __half2float(gh[r2 * 18 + fl]);
      float a3 = __half2float(gh[r3 * 18 + fl]);
      acc += (a0 + a1) + (a2 + a3);
      i += 8;
    }
    if (i + 4 <= e) {
      int r0 = adj[i + half];
      int r1 = adj[i + 2 + half];
      acc += __half2float(gh[r0 * 18 + fl]) + __half2float(gh[r1 * 18 + fl]);
      i += 4;
    }
    if (i + 2 <= e) {
      acc += __half2float(gh[adj[i + half] * 18 + fl]);
      i += 2;
    }
    if (i < e && half == 0) acc += __half2float(gh[adj[i] * 18 + fl]);
  }
  acc += __shfl_xor(acc, 32, 64);  // all 64 lanes participate
  if (act) {
    acc += __half2float(gh[node * 18 + fl]);  // self loop
    float v = fmaf(dis[node], acc, bias[fl]);
    if (half == 0) out[node * 18 + fl] = v;
  }
}

// ---------------- launch ----------------

extern "C" void kernel_launch(void* const* d_in, const int* in_sizes, int n_in,
                              void* d_out, int out_size, void* d_ws, size_t ws_size,
                              hipStream_t stream) {
  const float* x  = (const float*)d_in[0];
  const int*   ei = (const int*)d_in[1];
  const float* W1 = (const float*)d_in[2];
  const float* b1 = (const float*)d_in[3];
  const float* W2 = (const float*)d_in[4];
  const float* b2 = (const float*)d_in[5];
  const float* W3 = (const float*)d_in[6];
  const float* b3 = (const float*)d_in[7];
  const float* Wo = (const float*)d_in[8];
  const float* bo = (const float*)d_in[9];
  float* out = (float*)d_out;

  const int N = NODES;
  const int E = in_sizes[1] / 2;
  const int* rowp = ei;
  const int* colp = ei + E;

  char* p = (char*)d_ws;
  auto alloc = [&](size_t bytes) {
    void* r = (void*)p;
    p += (bytes + 255) & ~(size_t)255;
    return r;
  };
  int*   bcnt  = (int*)alloc((size_t)NBKT * 4);
  int*   bcurs = (int*)alloc((size_t)NBKT * 4);
  int*   boffs = (int*)alloc((size_t)(NBKT + 1) * 4);
  float* dis   = (float*)alloc((size_t)N * 4);
  int*   offs  = (int*)alloc((size_t)(N + 1) * 4);
  int*   adj   = (int*)alloc((size_t)E * 4);
  // recs (E*4 = 12.8MB) dead after csr_k; alias with fp16 gather table (N*64*2 = 12.8MB)
  u32*   recs  = (u32*)alloc((size_t)N * 64 * 2);
  u16*   gb    = (u16*)recs;
  float* h     = (float*)alloc((size_t)N * 64 * 4);   // fp32 hidden activations
  u16*   g4    = (u16*)alloc((size_t)N * 18 * 2);    // fp16 gather table, final layer

  zero_k<<<(NBKT + 255) / 256, 256, 0, stream>>>(bcnt, NBKT);
  bucket_hist_k<<<(E + HCHUNK - 1) / HCHUNK, 256, 0, stream>>>(colp, bcnt, E);
  bscan_k<<<1, 256, 0, stream>>>(bcnt, boffs, bcurs, NBKT, E);
  bucket_fill_k<<<(E + FCHUNK - 1) / FCHUNK, 256, 0, stream>>>(rowp, colp, bcurs, recs, E);
  csr_k<<<NBKT, 256, 0, stream>>>(recs, boffs, offs, adj, dis, N, E);

  int gG = (N + 127) / 128;   // 128 nodes per gemm block
  int gA = (N + 3) / 4;

  gemm64_k<100, 25><<<gG, 256, 0, stream>>>(x, W1, dis, gb, N);
  agg_f16_k<<<gA, 256, 0, stream>>>(gb, offs, adj, dis, b1, h, N);

  gemm64_k<64, 16><<<gG, 256, 0, stream>>>(h, W2, dis, gb, N);
  agg_f16_k<<<gA, 256, 0, stream>>>(gb, offs, adj, dis, b2, h, N);

  gemm64_k<64, 16><<<gG, 256, 0, stream>>>(h, W3, dis, gb, N);
  agg_f16_k<<<gA, 256, 0, stream>>>(gb, offs, adj, dis, b3, h, N);

  gemm18_k<<<gG, 256, 0, stream>>>(h, Wo, dis, g4, N);
  agg_f16o_k<<<gA, 256, 0, stream>>>(g4, offs, adj, dis, bo, out, N);
}

// Round 13
// 416.809 us; speedup vs baseline: 1.1436x; 1.0227x over previous
//
#include <hip/hip_runtime.h>
#include <hip/hip_fp16.h>

#define NODES 100000
#define NBKT 782            // ceil(100000/128) buckets of 128 cols
#define HCHUNK 8192         // edges per bucket_hist block
#define FCHUNK 4096         // edges per bucket_fill block (256 thr x 16)

typedef unsigned short u16;
typedef unsigned int u32;

__device__ __forceinline__ __half2 asH2(u32 v) {
  union { u32 u; __half2 h; } c; c.u = v; return c.h;
}

// ---------------- small utils ----------------

__global__ __launch_bounds__(256) void zero_k(int* __restrict__ p, int n) {
  int i = blockIdx.x * 256 + threadIdx.x;
  if (i < n) p[i] = 0;
}

// ---------------- bucket build ----------------

__global__ __launch_bounds__(256) void bucket_hist_k(const int* __restrict__ col,
                                                     int* __restrict__ bcnt, int E) {
  __shared__ int h[NBKT];
  int t = threadIdx.x;
  for (int i = t; i < NBKT; i += 256) h[i] = 0;
  __syncthreads();
  int base = blockIdx.x * HCHUNK;
#pragma unroll 4
  for (int j = 0; j < HCHUNK / 256; ++j) {
    int i = base + j * 256 + t;
    if (i < E) atomicAdd(&h[col[i] >> 7], 1);
  }
  __syncthreads();
  for (int i = t; i < NBKT; i += 256) {
    int c = h[i];
    if (c) atomicAdd(&bcnt[i], c);
  }
}

__global__ __launch_bounds__(256) void bscan_k(const int* __restrict__ bcnt,
                                               int* __restrict__ boffs,
                                               int* __restrict__ bcurs, int nb, int E) {
  __shared__ int lds[256];
  int t = threadIdx.x;
  int base = t * 4;
  int v[4];
#pragma unroll
  for (int j = 0; j < 4; ++j) v[j] = (base + j < nb) ? bcnt[base + j] : 0;
  int s = v[0] + v[1] + v[2] + v[3];
  lds[t] = s;
  __syncthreads();
  for (int off = 1; off < 256; off <<= 1) {
    int y = (t >= off) ? lds[t - off] : 0;
    __syncthreads();
    lds[t] += y;
    __syncthreads();
  }
  int excl = lds[t] - s;
#pragma unroll
  for (int j = 0; j < 4; ++j) {
    int i = base + j;
    if (i < nb) { boffs[i] = excl; bcurs[i] = excl; }
    excl += v[j];
  }
  if (t == 255) boffs[nb] = E;
}

// scatter packed records (colLow<<17 | row) into bucket regions.
__global__ __launch_bounds__(256) void bucket_fill_k(const int* __restrict__ row,
                                                     const int* __restrict__ col,
                                                     int* __restrict__ bcurs,
                                                     u32* __restrict__ recs, int E) {
  __shared__ int lcnt[NBKT];
  __shared__ int lbase[NBKT];
  int t = threadIdx.x;
  int base = blockIdx.x * FCHUNK;
  for (int i = t; i < NBKT; i += 256) lcnt[i] = 0;
  __syncthreads();
  u32 rec[FCHUNK / 256];
  u32 meta[FCHUNK / 256];
#pragma unroll
  for (int j = 0; j < FCHUNK / 256; ++j) {
    int i = base + j * 256 + t;
    if (i < E) {
      int r = row[i], c = col[i];
      int b = c >> 7;
      rec[j] = (u32)r | ((u32)(c & 127) << 17);
      int lr = atomicAdd(&lcnt[b], 1);
      meta[j] = (u32)lr | ((u32)b << 16);
    } else {
      meta[j] = 0xFFFFFFFFu;
    }
  }
  __syncthreads();
  for (int i = t; i < NBKT; i += 256) {
    int c = lcnt[i];
    lbase[i] = c ? atomicAdd(&bcurs[i], c) : 0;
  }
  __syncthreads();
#pragma unroll
  for (int j = 0; j < FCHUNK / 256; ++j) {
    if (meta[j] != 0xFFFFFFFFu) {
      int b = meta[j] >> 16;
      int lr = meta[j] & 0xFFFF;
      recs[lbase[b] + lr] = rec[j];
    }
  }
}

// records (bucketed by col) -> per-node CSR (offs, adj) + dis. One block per bucket.
__global__ __launch_bounds__(256) void csr_k(const u32* __restrict__ recs,
                                             const int* __restrict__ boffs,
                                             int* __restrict__ offs, int* __restrict__ adj,
                                             float* __restrict__ dis, int N, int E) {
  __shared__ int cnt[128];
  __shared__ int sa[128], sb[128];
  __shared__ int cur[128];
  int b = blockIdx.x, t = threadIdx.x;
  if (t < 128) cnt[t] = 0;
  __syncthreads();
  int s = boffs[b], e = boffs[b + 1];
  for (int i = s + t; i < e; i += 256) atomicAdd(&cnt[recs[i] >> 17], 1);
  __syncthreads();
  if (t < 128) sa[t] = cnt[t];
  __syncthreads();
#pragma unroll
  for (int off = 1; off < 128; off <<= 1) {
    if (t < 128) sb[t] = sa[t] + ((t >= off) ? sa[t - off] : 0);
    __syncthreads();
    if (t < 128) sa[t] = sb[t];
    __syncthreads();
  }
  if (t < 128) {
    int c = b * 128 + t;
    if (c < N) {
      int excl = sa[t] - cnt[t];
      offs[c] = s + excl;
      cur[t] = s + excl;
      dis[c] = rsqrtf((float)(cnt[t] + 1));  // +1 self loop
    }
  }
  if (b == 0 && t == 0) offs[N] = E;
  __syncthreads();
  for (int i = s + t; i < e; i += 256) {
    u32 r = recs[i];
    int p = atomicAdd(&cur[r >> 17], 1);
    adj[p] = (int)(r & 0x1FFFF);
  }
}

// ---------------- GEMM (NOUT=64): G[node,:] = (X[node,:] @ W) * dis[node], fp16 out ----------------
template <int K, int NK>
__global__ __launch_bounds__(256, 2) void gemm64_k(const float* __restrict__ X,
                                                   const float* __restrict__ W,
                                                   const float* __restrict__ dis,
                                                   u16* __restrict__ G, int n) {
  static_assert(K == NK * 4, "NT=4");
  __shared__ float ws[K * 64];
  int t = threadIdx.x;
  for (int i = t; i < K * 64; i += 256) ws[i] = W[i];
  __syncthreads();
  int q = t & 3, g = t >> 2;
  int b0 = blockIdx.x * 128;
  int n0 = b0 + g, n1 = b0 + 64 + g;
  int c0 = (n0 < n) ? n0 : 0, c1 = (n1 < n) ? n1 : 0;
  float xv0[NK], xv1[NK];
  const float* p0 = X + (size_t)c0 * K + q * NK;
  const float* p1 = X + (size_t)c1 * K + q * NK;
  if constexpr (NK % 4 == 0) {
#pragma unroll
    for (int i = 0; i < NK / 4; ++i) {
      *(float4*)&xv0[4 * i] = *(const float4*)(p0 + 4 * i);
      *(float4*)&xv1[4 * i] = *(const float4*)(p1 + 4 * i);
    }
  } else {
#pragma unroll
    for (int i = 0; i < NK; ++i) { xv0[i] = p0[i]; xv1[i] = p1[i]; }
  }
  float acc0[16], acc1[16];
#pragma unroll
  for (int j = 0; j < 16; ++j) { acc0[j] = 0.f; acc1[j] = 0.f; }
  for (int qq = 0; qq < 4; ++qq) {
    const float* wbase = ws + (size_t)qq * NK * 64 + q * 16;
#pragma unroll
    for (int i = 0; i < NK; ++i) {
      float a0 = __shfl(xv0[i], qq, 4);
      float a1 = __shfl(xv1[i], qq, 4);
      const float* wr = wbase + i * 64;
#pragma unroll
      for (int j = 0; j < 16; ++j) {
        float w = wr[j];
        acc0[j] = fmaf(a0, w, acc0[j]);
        acc1[j] = fmaf(a1, w, acc1[j]);
      }
    }
  }
  uint4* G4 = (uint4*)G;
  {
    if (n0 < n) {
      float sc = dis[n0];
      u32 os[8];
#pragma unroll
      for (int j = 0; j < 8; ++j) {
        u16 lo = __half_as_ushort(__float2half(acc0[2 * j] * sc));
        u16 hi = __half_as_ushort(__float2half(acc0[2 * j + 1] * sc));
        os[j] = (u32)lo | ((u32)hi << 16);
      }
      size_t rb = (size_t)n0 * 8 + q * 2;
      G4[rb]     = make_uint4(os[0], os[1], os[2], os[3]);
      G4[rb + 1] = make_uint4(os[4], os[5], os[6], os[7]);
    }
    if (n1 < n) {
      float sc = dis[n1];
      u32 os[8];
#pragma unroll
      for (int j = 0; j < 8; ++j) {
        u16 lo = __half_as_ushort(__float2half(acc1[2 * j] * sc));
        u16 hi = __half_as_ushort(__float2half(acc1[2 * j + 1] * sc));
        os[j] = (u32)lo | ((u32)hi << 16);
      }
      size_t rb = (size_t)n1 * 8 + q * 2;
      G4[rb]     = make_uint4(os[0], os[1], os[2], os[3]);
      G4[rb + 1] = make_uint4(os[4], os[5], os[6], os[7]);
    }
  }
}

// ---------------- GEMM (final, NOUT=18, fp16 out): 2 threads/node, outs split 10/8 ----------------
__global__ __launch_bounds__(256, 2) void gemm18_k(const float* __restrict__ X,  // K=64
                                                   const float* __restrict__ W,
                                                   const float* __restrict__ dis,
                                                   u16* __restrict__ G, int n) {
  __shared__ float ws[64 * 18];
  int t = threadIdx.x;
  for (int i = t; i < 64 * 18; i += 256) ws[i] = W[i];
  __syncthreads();
  int q = t & 1, g = t >> 1;
  int b0 = blockIdx.x * 128;
  int node = b0 + g;
  int cn = (node < n) ? node : 0;
  float xv[32];
  const float* p = X + (size_t)cn * 64 + q * 32;
#pragma unroll
  for (int i = 0; i < 8; ++i) *(float4*)&xv[4 * i] = *(const float4*)(p + 4 * i);
  int cnt = q ? 8 : 10;
  float acc[10];
#pragma unroll
  for (int j = 0; j < 10; ++j) acc[j] = 0.f;
  for (int qq = 0; qq < 2; ++qq) {
    const float* wbase = ws + (size_t)qq * 32 * 18 + q * 10;
#pragma unroll
    for (int i = 0; i < 32; ++i) {
      float a = __shfl(xv[i], qq, 2);
      const float* wr = wbase + i * 18;
#pragma unroll
      for (int j = 0; j < 10; ++j)
        if (j < cnt) acc[j] = fmaf(a, wr[j], acc[j]);
    }
  }
  if (node >= n) return;
  float sc = dis[node];
  u32* G32 = (u32*)G;
  if (q == 0) {
    u32 os[5];
#pragma unroll
    for (int j = 0; j < 5; ++j) {
      u16 lo = __half_as_ushort(__float2half(acc[2 * j] * sc));
      u16 hi = __half_as_ushort(__float2half(acc[2 * j + 1] * sc));
      os[j] = (u32)lo | ((u32)hi << 16);
    }
#pragma unroll
    for (int j = 0; j < 5; ++j) G32[(size_t)node * 9 + j] = os[j];
  } else {
    u32 os[4];
#pragma unroll
    for (int j = 0; j < 4; ++j) {
      u16 lo = __half_as_ushort(__float2half(acc[2 * j] * sc));
      u16 hi = __half_as_ushort(__float2half(acc[2 * j + 1] * sc));
      os[j] = (u32)lo | ((u32)hi << 16);
    }
#pragma unroll
    for (int j = 0; j < 4; ++j) G32[(size_t)node * 9 + 5 + j] = os[j];
  }
}

// ---------------- aggregation (hidden, fp16 table): 2 edges/wave-gather ----------------
// Ladder: 32 (16 gathers in flight) -> 16 (8) -> 8 (4) -> 4 (2) -> 2 -> 1.
// Two independent 16-element fp16 trees per 32-rung (same per-tree error as the 16-rung).
__global__ __launch_bounds__(256) void agg_f16_k(const u16* __restrict__ g,
                                                 const int* __restrict__ offs,
                                                 const int* __restrict__ adj,
                                                 const float* __restrict__ dis,
                                                 const float* __restrict__ bias,
                                                 float* __restrict__ out, int n) {
  int node = blockIdx.x * 4 + (threadIdx.x >> 6);
  int lane = threadIdx.x & 63;
  int half = lane >> 5, fl = lane & 31;
  if (node >= n) return;
  const u32* g32 = (const u32*)g;
  float acc0 = 0.f, acc1 = 0.f;
  int s = offs[node], e = offs[node + 1];
  int i = s;
  for (; i + 32 <= e; i += 32) {  // 16 gathers in flight per lane
    int r0 = adj[i + half],      r1 = adj[i + 2 + half];
    int r2 = adj[i + 4 + half],  r3 = adj[i + 6 + half];
    int r4 = adj[i + 8 + half],  r5 = adj[i + 10 + half];
    int r6 = adj[i + 12 + half], r7 = adj[i + 14 + half];
    int r8 = adj[i + 16 + half], r9 = adj[i + 18 + half];
    int rA = adj[i + 20 + half], rB = adj[i + 22 + half];
    int rC = adj[i + 24 + half], rD = adj[i + 26 + half];
    int rE = adj[i + 28 + half], rF = adj[i + 30 + half];
    u32 v0 = g32[(r0 << 5) + fl], v1 = g32[(r1 << 5) + fl];
    u32 v2 = g32[(r2 << 5) + fl], v3 = g32[(r3 << 5) + fl];
    u32 v4 = g32[(r4 << 5) + fl], v5 = g32[(r5 << 5) + fl];
    u32 v6 = g32[(r6 << 5) + fl], v7 = g32[(r7 << 5) + fl];
    u32 v8 = g32[(r8 << 5) + fl], v9 = g32[(r9 << 5) + fl];
    u32 vA = g32[(rA << 5) + fl], vB = g32[(rB << 5) + fl];
    u32 vC = g32[(rC << 5) + fl], vD = g32[(rD << 5) + fl];
    u32 vE = g32[(rE << 5) + fl], vF = g32[(rF << 5) + fl];
    __half2 sA = __hadd2(__hadd2(asH2(v0), asH2(v1)), __hadd2(asH2(v2), asH2(v3)));
    __half2 sB = __hadd2(__hadd2(asH2(v4), asH2(v5)), __hadd2(asH2(v6), asH2(v7)));
    float2 f1 = __half22float2(__hadd2(sA, sB));
    __half2 sC = __hadd2(__hadd2(asH2(v8), asH2(v9)), __hadd2(asH2(vA), asH2(vB)));
    __half2 sD = __hadd2(__hadd2(asH2(vC), asH2(vD)), __hadd2(asH2(vE), asH2(vF)));
    float2 f2 = __half22float2(__hadd2(sC, sD));
    acc0 += f1.x + f2.x;
    acc1 += f1.y + f2.y;
  }
  if (i + 16 <= e) {  // 8 gathers in flight
    int r0 = adj[i + half],      r1 = adj[i + 2 + half];
    int r2 = adj[i + 4 + half],  r3 = adj[i + 6 + half];
    int r4 = adj[i + 8 + half],  r5 = adj[i + 10 + half];
    int r6 = adj[i + 12 + half], r7 = adj[i + 14 + half];
    u32 v0 = g32[(r0 << 5) + fl], v1 = g32[(r1 << 5) + fl];
    u32 v2 = g32[(r2 << 5) + fl], v3 = g32[(r3 << 5) + fl];
    u32 v4 = g32[(r4 << 5) + fl], v5 = g32[(r5 << 5) + fl];
    u32 v6 = g32[(r6 << 5) + fl], v7 = g32[(r7 << 5) + fl];
    __half2 sA = __hadd2(__hadd2(asH2(v0), asH2(v1)), __hadd2(asH2(v2), asH2(v3)));
    __half2 sB = __hadd2(__hadd2(asH2(v4), asH2(v5)), __hadd2(asH2(v6), asH2(v7)));
    float2 f = __half22float2(__hadd2(sA, sB));
    acc0 += f.x;
    acc1 += f.y;
    i += 16;
  }
  if (i + 8 <= e) {  // 4 gathers in flight
    int r0 = adj[i + half];
    int r1 = adj[i + 2 + half];
    int r2 = adj[i + 4 + half];
    int r3 = adj[i + 6 + half];
    u32 v0 = g32[(r0 << 5) + fl];
    u32 v1 = g32[(r1 << 5) + fl];
    u32 v2 = g32[(r2 << 5) + fl];
    u32 v3 = g32[(r3 << 5) + fl];
    float2 f = __half22float2(__hadd2(__hadd2(asH2(v0), asH2(v1)),
                                      __hadd2(asH2(v2), asH2(v3))));
    acc0 += f.x;
    acc1 += f.y;
    i += 8;
  }
  if (i + 4 <= e) {  // 2 gathers in flight
    int r0 = adj[i + half];
    int r1 = adj[i + 2 + half];
    u32 v0 = g32[(r0 << 5) + fl];
    u32 v1 = g32[(r1 << 5) + fl];
    float2 f = __half22float2(__hadd2(asH2(v0), asH2(v1)));
    acc0 += f.x;
    acc1 += f.y;
    i += 4;
  }
  if (i + 2 <= e) {
    int r = adj[i + half];
    float2 f = __half22float2(asH2(g32[(r << 5) + fl]));
    acc0 += f.x;
    acc1 += f.y;
    i += 2;
  }
  if (i < e) {  // odd tail edge: only half 0 counts it
    int r = adj[i];
    float2 f = __half22float2(asH2(g32[(r << 5) + fl]));
    if (half == 0) { acc0 += f.x; acc1 += f.y; }
  }
  acc0 += __shfl_xor(acc0, 32, 64);
  acc1 += __shfl_xor(acc1, 32, 64);
  float2 fs = __half22float2(asH2(g32[(node << 5) + fl]));  // self loop (pre-scaled)
  acc0 += fs.x;
  acc1 += fs.y;
  float d = dis[node];
  float o0 = fmaxf(fmaf(d, acc0, bias[2 * fl]), 0.f);
  float o1 = fmaxf(fmaf(d, acc1, bias[2 * fl + 1]), 0.f);
  if (half == 0) {
    float2 st = {o0, o1};
    *(float2*)(out + node * 64 + 2 * fl) = st;
  }
}

// ---------------- aggregation (final, 18-wide fp16 table): 3 edges per wave-gather ----------------
// 54/64 lanes active; ladder 24 (8 gathers in flight) -> 12 (4) -> 6 (2) -> 3 -> tail.
__global__ __launch_bounds__(256) void agg_f16o_k(const u16* __restrict__ g,
                                                  const int* __restrict__ offs,
                                                  const int* __restrict__ adj,
                                                  const float* __restrict__ dis,
                                                  const float* __restrict__ bias,
                                                  float* __restrict__ out, int n) {
  int node = blockIdx.x * 4 + (threadIdx.x >> 6);
  int lane = threadIdx.x & 63;
  int e3 = lane / 18;              // 0..2 active, 3 = idle (lanes 54..63)
  int f = lane - e3 * 18;
  if (node >= n) return;
  const __half* gh = (const __half*)g;
  bool act = e3 < 3;
  float acc = 0.f;
  int s = offs[node], e = offs[node + 1];
  int i = s;
  if (act) {
    for (; i + 24 <= e; i += 24) {  // 8 triple-gathers in flight
      int r0 = adj[i + e3],      r1 = adj[i + 3 + e3];
      int r2 = adj[i + 6 + e3],  r3 = adj[i + 9 + e3];
      int r4 = adj[i + 12 + e3], r5 = adj[i + 15 + e3];
      int r6 = adj[i + 18 + e3], r7 = adj[i + 21 + e3];
      float x0 = __half2float(gh[r0 * 18 + f]);
      float x1 = __half2float(gh[r1 * 18 + f]);
      float x2 = __half2float(gh[r2 * 18 + f]);
      float x3 = __half2float(gh[r3 * 18 + f]);
      float x4 = __half2float(gh[r4 * 18 + f]);
      float x5 = __half2float(gh[r5 * 18 + f]);
      float x6 = __half2float(gh[r6 * 18 + f]);
      float x7 = __half2float(gh[r7 * 18 + f]);
      acc += ((x0 + x1) + (x2 + x3)) + ((x4 + x5) + (x6 + x7));
    }
    if (i + 12 <= e) {  // 4 in flight
      int r0 = adj[i + e3],     r1 = adj[i + 3 + e3];
      int r2 = adj[i + 6 + e3], r3 = adj[i + 9 + e3];
      float x0 = __half2float(gh[r0 * 18 + f]);
      float x1 = __half2float(gh[r1 * 18 + f]);
      float x2 = __half2float(gh[r2 * 18 + f]);
      float x3 = __half2float(gh[r3 * 18 + f]);
      acc += (x0 + x1) + (x2 + x3);
      i += 12;
    }
    if (i + 6 <= e) {  // 2 in flight
      int r0 = adj[i + e3], r1 = adj[i + 3 + e3];
      acc += __half2float(gh[r0 * 18 + f]) + __half2float(gh[r1 * 18 + f]);
      i += 6;
    }
    if (i + 3 <= e) {
      acc += __half2float(gh[adj[i + e3] * 18 + f]);
      i += 3;
    }
    if (i < e) {  // tail m in 1..2
      int m = e - i;
      int idx = (e3 < m) ? (i + e3) : i;
      float x = __half2float(gh[adj[idx] * 18 + f]);
      if (e3 < m) acc += x;
    }
  }
  // reduce across the 3 edge-groups (lanes l, l+18, l+36) — all lanes execute
  float t1 = __shfl(acc, lane + 18, 64);
  float t2 = __shfl(acc, lane + 36, 64);
  if (lane < 18) {
    float total = acc + t1 + t2;
    total += __half2float(gh[node * 18 + lane]);  // self loop
    float v = fmaf(dis[node], total, bias[lane]);
    out[node * 18 + lane] = v;
  }
}

// ---------------- launch ----------------

extern "C" void kernel_launch(void* const* d_in, const int* in_sizes, int n_in,
                              void* d_out, int out_size, void* d_ws, size_t ws_size,
                              hipStream_t stream) {
  const float* x  = (const float*)d_in[0];
  const int*   ei = (const int*)d_in[1];
  const float* W1 = (const float*)d_in[2];
  const float* b1 = (const float*)d_in[3];
  const float* W2 = (const float*)d_in[4];
  const float* b2 = (const float*)d_in[5];
  const float* W3 = (const float*)d_in[6];
  const float* b3 = (const float*)d_in[7];
  const float* Wo = (const float*)d_in[8];
  const float* bo = (const float*)d_in[9];
  float* out = (float*)d_out;

  const int N = NODES;
  const int E = in_sizes[1] / 2;
  const int* rowp = ei;
  const int* colp = ei + E;

  char* p = (char*)d_ws;
  auto alloc = [&](size_t bytes) {
    void* r = (void*)p;
    p += (bytes + 255) & ~(size_t)255;
    return r;
  };
  int*   bcnt  = (int*)alloc((size_t)NBKT * 4);
  int*   bcurs = (int*)alloc((size_t)NBKT * 4);
  int*   boffs = (int*)alloc((size_t)(NBKT + 1) * 4);
  float* dis   = (float*)alloc((size_t)N * 4);
  int*   offs  = (int*)alloc((size_t)(N + 1) * 4);
  int*   adj   = (int*)alloc((size_t)E * 4);
  // recs (E*4 = 12.8MB) dead after csr_k; alias with fp16 gather table (N*64*2 = 12.8MB)
  u32*   recs  = (u32*)alloc((size_t)N * 64 * 2);
  u16*   gb    = (u16*)recs;
  float* h     = (float*)alloc((size_t)N * 64 * 4);   // fp32 hidden activations
  u16*   g4    = (u16*)alloc((size_t)N * 18 * 2);    // fp16 gather table, final layer

  zero_k<<<(NBKT + 255) / 256, 256, 0, stream>>>(bcnt, NBKT);
  bucket_hist_k<<<(E + HCHUNK - 1) / HCHUNK, 256, 0, stream>>>(colp, bcnt, E);
  bscan_k<<<1, 256, 0, stream>>>(bcnt, boffs, bcurs, NBKT, E);
  bucket_fill_k<<<(E + FCHUNK - 1) / FCHUNK, 256, 0, stream>>>(rowp, colp, bcurs, recs, E);
  csr_k<<<NBKT, 256, 0, stream>>>(recs, boffs, offs, adj, dis, N, E);

  int gG = (N + 127) / 128;   // 128 nodes per gemm block
  int gA = (N + 3) / 4;

  gemm64_k<100, 25><<<gG, 256, 0, stream>>>(x, W1, dis, gb, N);
  agg_f16_k<<<gA, 256, 0, stream>>>(gb, offs, adj, dis, b1, h, N);

  gemm64_k<64, 16><<<gG, 256, 0, stream>>>(h, W2, dis, gb, N);
  agg_f16_k<<<gA, 256, 0, stream>>>(gb, offs, adj, dis, b2, h, N);

  gemm64_k<64, 16><<<gG, 256, 0, stream>>>(h, W3, dis, gb, N);
  agg_f16_k<<<gA, 256, 0, stream>>>(gb, offs, adj, dis, b3, h, N);

  gemm18_k<<<gG, 256, 0, stream>>>(h, Wo, dis, g4, N);
  agg_f16o_k<<<gA, 256, 0, stream>>>(g4, offs, adj, dis, bo, out, N);
}

// Round 14
// 415.357 us; speedup vs baseline: 1.1476x; 1.0035x over previous
//
#include <hip/hip_runtime.h>
#include <hip/hip_fp16.h>

#define NODES 100000
#define NBKT 782            // ceil(100000/128) buckets of 128 cols
#define HCHUNK 8192         // edges per bucket_hist block
#define FCHUNK 4096         // edges per bucket_fill block (256 thr x 16)

typedef unsigned short u16;
typedef unsigned int u32;

__device__ __forceinline__ __half2 asH2(u32 v) {
  union { u32 u; __half2 h; } c; c.u = v; return c.h;
}

// ---------------- small utils ----------------

__global__ __launch_bounds__(256) void zero_k(int* __restrict__ p, int n) {
  int i = blockIdx.x * 256 + threadIdx.x;
  if (i < n) p[i] = 0;
}

// ---------------- bucket build ----------------

__global__ __launch_bounds__(256) void bucket_hist_k(const int* __restrict__ col,
                                                     int* __restrict__ bcnt, int E) {
  __shared__ int h[NBKT];
  int t = threadIdx.x;
  for (int i = t; i < NBKT; i += 256) h[i] = 0;
  __syncthreads();
  int base = blockIdx.x * HCHUNK;
#pragma unroll 4
  for (int j = 0; j < HCHUNK / 256; ++j) {
    int i = base + j * 256 + t;
    if (i < E) atomicAdd(&h[col[i] >> 7], 1);
  }
  __syncthreads();
  for (int i = t; i < NBKT; i += 256) {
    int c = h[i];
    if (c) atomicAdd(&bcnt[i], c);
  }
}

__global__ __launch_bounds__(256) void bscan_k(const int* __restrict__ bcnt,
                                               int* __restrict__ boffs,
                                               int* __restrict__ bcurs, int nb, int E) {
  __shared__ int lds[256];
  int t = threadIdx.x;
  int base = t * 4;
  int v[4];
#pragma unroll
  for (int j = 0; j < 4; ++j) v[j] = (base + j < nb) ? bcnt[base + j] : 0;
  int s = v[0] + v[1] + v[2] + v[3];
  lds[t] = s;
  __syncthreads();
  for (int off = 1; off < 256; off <<= 1) {
    int y = (t >= off) ? lds[t - off] : 0;
    __syncthreads();
    lds[t] += y;
    __syncthreads();
  }
  int excl = lds[t] - s;
#pragma unroll
  for (int j = 0; j < 4; ++j) {
    int i = base + j;
    if (i < nb) { boffs[i] = excl; bcurs[i] = excl; }
    excl += v[j];
  }
  if (t == 255) boffs[nb] = E;
}

// scatter packed records (colLow<<17 | row) into bucket regions.
__global__ __launch_bounds__(256) void bucket_fill_k(const int* __restrict__ row,
                                                     const int* __restrict__ col,
                                                     int* __restrict__ bcurs,
                                                     u32* __restrict__ recs, int E) {
  __shared__ int lcnt[NBKT];
  __shared__ int lbase[NBKT];
  int t = threadIdx.x;
  int base = blockIdx.x * FCHUNK;
  for (int i = t; i < NBKT; i += 256) lcnt[i] = 0;
  __syncthreads();
  u32 rec[FCHUNK / 256];
  u32 meta[FCHUNK / 256];
#pragma unroll
  for (int j = 0; j < FCHUNK / 256; ++j) {
    int i = base + j * 256 + t;
    if (i < E) {
      int r = row[i], c = col[i];
      int b = c >> 7;
      rec[j] = (u32)r | ((u32)(c & 127) << 17);
      int lr = atomicAdd(&lcnt[b], 1);
      meta[j] = (u32)lr | ((u32)b << 16);
    } else {
      meta[j] = 0xFFFFFFFFu;
    }
  }
  __syncthreads();
  for (int i = t; i < NBKT; i += 256) {
    int c = lcnt[i];
    lbase[i] = c ? atomicAdd(&bcurs[i], c) : 0;
  }
  __syncthreads();
#pragma unroll
  for (int j = 0; j < FCHUNK / 256; ++j) {
    if (meta[j] != 0xFFFFFFFFu) {
      int b = meta[j] >> 16;
      int lr = meta[j] & 0xFFFF;
      recs[lbase[b] + lr] = rec[j];
    }
  }
}

// records (bucketed by col) -> per-node CSR (offs, adj) + dis. One block per bucket.
__global__ __launch_bounds__(256) void csr_k(const u32* __restrict__ recs,
                                             const int* __restrict__ boffs,
                                             int* __restrict__ offs, int* __restrict__ adj,
                                             float* __restrict__ dis, int N, int E) {
  __shared__ int cnt[128];
  __shared__ int sa[128], sb[128];
  __shared__ int cur[128];
  int b = blockIdx.x, t = threadIdx.x;
  if (t < 128) cnt[t] = 0;
  __syncthreads();
  int s = boffs[b], e = boffs[b + 1];
  for (int i = s + t; i < e; i += 256) atomicAdd(&cnt[recs[i] >> 17], 1);
  __syncthreads();
  if (t < 128) sa[t] = cnt[t];
  __syncthreads();
#pragma unroll
  for (int off = 1; off < 128; off <<= 1) {
    if (t < 128) sb[t] = sa[t] + ((t >= off) ? sa[t - off] : 0);
    __syncthreads();
    if (t < 128) sa[t] = sb[t];
    __syncthreads();
  }
  if (t < 128) {
    int c = b * 128 + t;
    if (c < N) {
      int excl = sa[t] - cnt[t];
      offs[c] = s + excl;
      cur[t] = s + excl;
      dis[c] = rsqrtf((float)(cnt[t] + 1));  // +1 self loop
    }
  }
  if (b == 0 && t == 0) offs[N] = E;
  __syncthreads();
  for (int i = s + t; i < e; i += 256) {
    u32 r = recs[i];
    int p = atomicAdd(&cur[r >> 17], 1);
    adj[p] = (int)(r & 0x1FFFF);
  }
}

// ---------------- GEMM (NOUT=64): G[node,:] = (X[node,:] @ W) * dis[node], fp16 out ----------------
template <int K, int NK>
__global__ __launch_bounds__(256, 2) void gemm64_k(const float* __restrict__ X,
                                                   const float* __restrict__ W,
                                                   const float* __restrict__ dis,
                                                   u16* __restrict__ G, int n) {
  static_assert(K == NK * 4, "NT=4");
  __shared__ float ws[K * 64];
  int t = threadIdx.x;
  for (int i = t; i < K * 64; i += 256) ws[i] = W[i];
  __syncthreads();
  int q = t & 3, g = t >> 2;
  int b0 = blockIdx.x * 128;
  int n0 = b0 + g, n1 = b0 + 64 + g;
  int c0 = (n0 < n) ? n0 : 0, c1 = (n1 < n) ? n1 : 0;
  float xv0[NK], xv1[NK];
  const float* p0 = X + (size_t)c0 * K + q * NK;
  const float* p1 = X + (size_t)c1 * K + q * NK;
  if constexpr (NK % 4 == 0) {
#pragma unroll
    for (int i = 0; i < NK / 4; ++i) {
      *(float4*)&xv0[4 * i] = *(const float4*)(p0 + 4 * i);
      *(float4*)&xv1[4 * i] = *(const float4*)(p1 + 4 * i);
    }
  } else {
#pragma unroll
    for (int i = 0; i < NK; ++i) { xv0[i] = p0[i]; xv1[i] = p1[i]; }
  }
  float acc0[16], acc1[16];
#pragma unroll
  for (int j = 0; j < 16; ++j) { acc0[j] = 0.f; acc1[j] = 0.f; }
  for (int qq = 0; qq < 4; ++qq) {
    const float* wbase = ws + (size_t)qq * NK * 64 + q * 16;
#pragma unroll
    for (int i = 0; i < NK; ++i) {
      float a0 = __shfl(xv0[i], qq, 4);
      float a1 = __shfl(xv1[i], qq, 4);
      const float* wr = wbase + i * 64;
#pragma unroll
      for (int j = 0; j < 16; ++j) {
        float w = wr[j];
        acc0[j] = fmaf(a0, w, acc0[j]);
        acc1[j] = fmaf(a1, w, acc1[j]);
      }
    }
  }
  uint4* G4 = (uint4*)G;
  {
    if (n0 < n) {
      float sc = dis[n0];
      u32 os[8];
#pragma unroll
      for (int j = 0; j < 8; ++j) {
        u16 lo = __half_as_ushort(__float2half(acc0[2 * j] * sc));
        u16 hi = __half_as_ushort(__float2half(acc0[2 * j + 1] * sc));
        os[j] = (u32)lo | ((u32)hi << 16);
      }
      size_t rb = (size_t)n0 * 8 + q * 2;
      G4[rb]     = make_uint4(os[0], os[1], os[2], os[3]);
      G4[rb + 1] = make_uint4(os[4], os[5], os[6], os[7]);
    }
    if (n1 < n) {
      float sc = dis[n1];
      u32 os[8];
#pragma unroll
      for (int j = 0; j < 8; ++j) {
        u16 lo = __half_as_ushort(__float2half(acc1[2 * j] * sc));
        u16 hi = __half_as_ushort(__float2half(acc1[2 * j + 1] * sc));
        os[j] = (u32)lo | ((u32)hi << 16);
      }
      size_t rb = (size_t)n1 * 8 + q * 2;
      G4[rb]     = make_uint4(os[0], os[1], os[2], os[3]);
      G4[rb + 1] = make_uint4(os[4], os[5], os[6], os[7]);
    }
  }
}

// ---------------- GEMM (final, NOUT=18, fp16 out): 2 threads/node, outs split 10/8 ----------------
__global__ __launch_bounds__(256, 2) void gemm18_k(const float* __restrict__ X,  // K=64
                                                   const float* __restrict__ W,
                                                   const float* __restrict__ dis,
                                                   u16* __restrict__ G, int n) {
  __shared__ float ws[64 * 18];
  int t = threadIdx.x;
  for (int i = t; i < 64 * 18; i += 256) ws[i] = W[i];
  __syncthreads();
  int q = t & 1, g = t >> 1;
  int b0 = blockIdx.x * 128;
  int node = b0 + g;
  int cn = (node < n) ? node : 0;
  float xv[32];
  const float* p = X + (size_t)cn * 64 + q * 32;
#pragma unroll
  for (int i = 0; i < 8; ++i) *(float4*)&xv[4 * i] = *(const float4*)(p + 4 * i);
  int cnt = q ? 8 : 10;
  float acc[10];
#pragma unroll
  for (int j = 0; j < 10; ++j) acc[j] = 0.f;
  for (int qq = 0; qq < 2; ++qq) {
    const float* wbase = ws + (size_t)qq * 32 * 18 + q * 10;
#pragma unroll
    for (int i = 0; i < 32; ++i) {
      float a = __shfl(xv[i], qq, 2);
      const float* wr = wbase + i * 18;
#pragma unroll
      for (int j = 0; j < 10; ++j)
        if (j < cnt) acc[j] = fmaf(a, wr[j], acc[j]);
    }
  }
  if (node >= n) return;
  float sc = dis[node];
  u32* G32 = (u32*)G;
  if (q == 0) {
    u32 os[5];
#pragma unroll
    for (int j = 0; j < 5; ++j) {
      u16 lo = __half_as_ushort(__float2half(acc[2 * j] * sc));
      u16 hi = __half_as_ushort(__float2half(acc[2 * j + 1] * sc));
      os[j] = (u32)lo | ((u32)hi << 16);
    }
#pragma unroll
    for (int j = 0; j < 5; ++j) G32[(size_t)node * 9 + j] = os[j];
  } else {
    u32 os[4];
#pragma unroll
    for (int j = 0; j < 4; ++j) {
      u16 lo = __half_as_ushort(__float2half(acc[2 * j] * sc));
      u16 hi = __half_as_ushort(__float2half(acc[2 * j + 1] * sc));
      os[j] = (u32)lo | ((u32)hi << 16);
    }
#pragma unroll
    for (int j = 0; j < 4; ++j) G32[(size_t)node * 9 + 5 + j] = os[j];
  }
}

// ---------------- aggregation (hidden, fp16 table): 2 edges/wave-gather ----------------
// Ladder: 32 (16 gathers in flight) -> 16 (8) -> 8 (4) -> 4 (2) -> 2 -> 1.
// Two independent 16-element fp16 trees per 32-rung (same per-tree error as the 16-rung).
__global__ __launch_bounds__(256) void agg_f16_k(const u16* __restrict__ g,
                                                 const int* __restrict__ offs,
                                                 const int* __restrict__ adj,
                                                 const float* __restrict__ dis,
                                                 const float* __restrict__ bias,
                                                 float* __restrict__ out, int n) {
  int node = blockIdx.x * 4 + (threadIdx.x >> 6);
  int lane = threadIdx.x & 63;
  int half = lane >> 5, fl = lane & 31;
  if (node >= n) return;
  const u32* g32 = (const u32*)g;
  float acc0 = 0.f, acc1 = 0.f;
  int s = offs[node], e = offs[node + 1];
  int i = s;
  for (; i + 32 <= e; i += 32) {  // 16 gathers in flight per lane
    int r0 = adj[i + half],      r1 = adj[i + 2 + half];
    int r2 = adj[i + 4 + half],  r3 = adj[i + 6 + half];
    int r4 = adj[i + 8 + half],  r5 = adj[i + 10 + half];
    int r6 = adj[i + 12 + half], r7 = adj[i + 14 + half];
    int r8 = adj[i + 16 + half], r9 = adj[i + 18 + half];
    int rA = adj[i + 20 + half], rB = adj[i + 22 + half];
    int rC = adj[i + 24 + half], rD = adj[i + 26 + half];
    int rE = adj[i + 28 + half], rF = adj[i + 30 + half];
    u32 v0 = g32[(r0 << 5) + fl], v1 = g32[(r1 << 5) + fl];
    u32 v2 = g32[(r2 << 5) + fl], v3 = g32[(r3 << 5) + fl];
    u32 v4 = g32[(r4 << 5) + fl], v5 = g32[(r5 << 5) + fl];
    u32 v6 = g32[(r6 << 5) + fl], v7 = g32[(r7 << 5) + fl];
    u32 v8 = g32[(r8 << 5) + fl], v9 = g32[(r9 << 5) + fl];
    u32 vA = g32[(rA << 5) + fl], vB = g32[(rB << 5) + fl];
    u32 vC = g32[(rC << 5) + fl], vD = g32[(rD << 5) + fl];
    u32 vE = g32[(rE << 5) + fl], vF = g32[(rF << 5) + fl];
    __half2 sA = __hadd2(__hadd2(asH2(v0), asH2(v1)), __hadd2(asH2(v2), asH2(v3)));
    __half2 sB = __hadd2(__hadd2(asH2(v4), asH2(v5)), __hadd2(asH2(v6), asH2(v7)));
    float2 f1 = __half22float2(__hadd2(sA, sB));
    __half2 sC = __hadd2(__hadd2(asH2(v8), asH2(v9)), __hadd2(asH2(vA), asH2(vB)));
    __half2 sD = __hadd2(__hadd2(asH2(vC), asH2(vD)), __hadd2(asH2(vE), asH2(vF)));
    float2 f2 = __half22float2(__hadd2(sC, sD));
    acc0 += f1.x + f2.x;
    acc1 += f1.y + f2.y;
  }
  if (i + 16 <= e) {  // 8 gathers in flight
    int r0 = adj[i + half],      r1 = adj[i + 2 + half];
    int r2 = adj[i + 4 + half],  r3 = adj[i + 6 + half];
    int r4 = adj[i + 8 + half],  r5 = adj[i + 10 + half];
    int r6 = adj[i + 12 + half], r7 = adj[i + 14 + half];
    u32 v0 = g32[(r0 << 5) + fl], v1 = g32[(r1 << 5) + fl];
    u32 v2 = g32[(r2 << 5) + fl], v3 = g32[(r3 << 5) + fl];
    u32 v4 = g32[(r4 << 5) + fl], v5 = g32[(r5 << 5) + fl];
    u32 v6 = g32[(r6 << 5) + fl], v7 = g32[(r7 << 5) + fl];
    __half2 sA = __hadd2(__hadd2(asH2(v0), asH2(v1)), __hadd2(asH2(v2), asH2(v3)));
    __half2 sB = __hadd2(__hadd2(asH2(v4), asH2(v5)), __hadd2(asH2(v6), asH2(v7)));
    float2 f = __half22float2(__hadd2(sA, sB));
    acc0 += f.x;
    acc1 += f.y;
    i += 16;
  }
  if (i + 8 <= e) {  // 4 gathers in flight
    int r0 = adj[i + half];
    int r1 = adj[i + 2 + half];
    int r2 = adj[i + 4 + half];
    int r3 = adj[i + 6 + half];
    u32 v0 = g32[(r0 << 5) + fl];
    u32 v1 = g32[(r1 << 5) + fl];
    u32 v2 = g32[(r2 << 5) + fl];
    u32 v3 = g32[(r3 << 5) + fl];
    float2 f = __half22float2(__hadd2(__hadd2(asH2(v0), asH2(v1)),
                                      __hadd2(asH2(v2), asH2(v3))));
    acc0 += f.x;
    acc1 += f.y;
    i += 8;
  }
  if (i + 4 <= e) {  // 2 gathers in flight
    int r0 = adj[i + half];
    int r1 = adj[i + 2 + half];
    u32 v0 = g32[(r0 << 5) + fl];
    u32 v1 = g32[(r1 << 5) + fl];
    float2 f = __half22float2(__hadd2(asH2(v0), asH2(v1)));
    acc0 += f.x;
    acc1 += f.y;
    i += 4;
  }
  if (i + 2 <= e) {
    int r = adj[i + half];
    float2 f = __half22float2(asH2(g32[(r << 5) + fl]));
    acc0 += f.x;
    acc1 += f.y;
    i += 2;
  }
  if (i < e) {  // odd tail edge: only half 0 counts it
    int r = adj[i];
    float2 f = __half22float2(asH2(g32[(r << 5) + fl]));
    if (half == 0) { acc0 += f.x; acc1 += f.y; }
  }
  acc0 += __shfl_xor(acc0, 32, 64);
  acc1 += __shfl_xor(acc1, 32, 64);
  float2 fs = __half22float2(asH2(g32[(node << 5) + fl]));  // self loop (pre-scaled)
  acc0 += fs.x;
  acc1 += fs.y;
  float d = dis[node];
  float o0 = fmaxf(fmaf(d, acc0, bias[2 * fl]), 0.f);
  float o1 = fmaxf(fmaf(d, acc1, bias[2 * fl + 1]), 0.f);
  if (half == 0) {
    float2 st = {o0, o1};
    *(float2*)(out + node * 64 + 2 * fl) = st;
  }
}

// ---------------- aggregation (final, 18-wide fp16 table): 3 edges per wave-gather ----------------
// 54/64 lanes active; ladder 24 (8 gathers in flight) -> 12 (4) -> 6 (2) -> 3 -> tail.
__global__ __launch_bounds__(256) void agg_f16o_k(const u16* __restrict__ g,
                                                  const int* __restrict__ offs,
                                                  const int* __restrict__ adj,
                                                  const float* __restrict__ dis,
                                                  const float* __restrict__ bias,
                                                  float* __restrict__ out, int n) {
  int node = blockIdx.x * 4 + (threadIdx.x >> 6);
  int lane = threadIdx.x & 63;
  int e3 = lane / 18;              // 0..2 active, 3 = idle (lanes 54..63)
  int f = lane - e3 * 18;
  if (node >= n) return;
  const __half* gh = (const __half*)g;
  bool act = e3 < 3;
  float acc = 0.f;
  int s = offs[node], e = offs[node + 1];
  int i = s;
  if (act) {
    for (; i + 24 <= e; i += 24) {  // 8 triple-gathers in flight
      int r0 = adj[i + e3],      r1 = adj[i + 3 + e3];
      int r2 = adj[i + 6 + e3],  r3 = adj[i + 9 + e3];
      int r4 = adj[i + 12 + e3], r5 = adj[i + 15 + e3];
      int r6 = adj[i + 18 + e3], r7 = adj[i + 21 + e3];
      float x0 = __half2float(gh[r0 * 18 + f]);
      float x1 = __half2float(gh[r1 * 18 + f]);
      float x2 = __half2float(gh[r2 * 18 + f]);
      float x3 = __half2float(gh[r3 * 18 + f]);
      float x4 = __half2float(gh[r4 * 18 + f]);
      float x5 = __half2float(gh[r5 * 18 + f]);
      float x6 = __half2float(gh[r6 * 18 + f]);
      float x7 = __half2float(gh[r7 * 18 + f]);
      acc += ((x0 + x1) + (x2 + x3)) + ((x4 + x5) + (x6 + x7));
    }
    if (i + 12 <= e) {  // 4 in flight
      int r0 = adj[i + e3],     r1 = adj[i + 3 + e3];
      int r2 = adj[i + 6 + e3], r3 = adj[i + 9 + e3];
      float x0 = __half2float(gh[r0 * 18 + f]);
      float x1 = __half2float(gh[r1 * 18 + f]);
      float x2 = __half2float(gh[r2 * 18 + f]);
      float x3 = __half2float(gh[r3 * 18 + f]);
      acc += (x0 + x1) + (x2 + x3);
      i += 12;
    }
    if (i + 6 <= e) {  // 2 in flight
      int r0 = adj[i + e3], r1 = adj[i + 3 + e3];
      acc += __half2float(gh[r0 * 18 + f]) + __half2float(gh[r1 * 18 + f]);
      i += 6;
    }
    if (i + 3 <= e) {
      acc += __half2float(gh[adj[i + e3] * 18 + f]);
      i += 3;
    }
    if (i < e) {  // tail m in 1..2
      int m = e - i;
      int idx = (e3 < m) ? (i + e3) : i;
      float x = __half2float(gh[adj[idx] * 18 + f]);
      if (e3 < m) acc += x;
    }
  }
  // reduce across the 3 edge-groups (lanes l, l+18, l+36) — all lanes execute
  float t1 = __shfl(acc, lane + 18, 64);
  float t2 = __shfl(acc, lane + 36, 64);
  if (lane < 18) {
    float total = acc + t1 + t2;
    total += __half2float(gh[node * 18 + lane]);  // self loop
    float v = fmaf(dis[node], total, bias[lane]);
    out[node * 18 + lane] = v;
  }
}

// ---------------- launch ----------------

extern "C" void kernel_launch(void* const* d_in, const int* in_sizes, int n_in,
                              void* d_out, int out_size, void* d_ws, size_t ws_size,
                              hipStream_t stream) {
  const float* x  = (const float*)d_in[0];
  const int*   ei = (const int*)d_in[1];
  const float* W1 = (const float*)d_in[2];
  const float* b1 = (const float*)d_in[3];
  const float* W2 = (const float*)d_in[4];
  const float* b2 = (const float*)d_in[5];
  const float* W3 = (const float*)d_in[6];
  const float* b3 = (const float*)d_in[7];
  const float* Wo = (const float*)d_in[8];
  const float* bo = (const float*)d_in[9];
  float* out = (float*)d_out;

  const int N = NODES;
  const int E = in_sizes[1] / 2;
  const int* rowp = ei;
  const int* colp = ei + E;

  char* p = (char*)d_ws;
  auto alloc = [&](size_t bytes) {
    void* r = (void*)p;
    p += (bytes + 255) & ~(size_t)255;
    return r;
  };
  int*   bcnt  = (int*)alloc((size_t)NBKT * 4);
  int*   bcurs = (int*)alloc((size_t)NBKT * 4);
  int*   boffs = (int*)alloc((size_t)(NBKT + 1) * 4);
  float* dis   = (float*)alloc((size_t)N * 4);
  int*   offs  = (int*)alloc((size_t)(N + 1) * 4);
  int*   adj   = (int*)alloc((size_t)E * 4);
  // recs (E*4 = 12.8MB) dead after csr_k; alias with fp16 gather table (N*64*2 = 12.8MB)
  u32*   recs  = (u32*)alloc((size_t)N * 64 * 2);
  u16*   gb    = (u16*)recs;
  float* h     = (float*)alloc((size_t)N * 64 * 4);   // fp32 hidden activations
  u16*   g4    = (u16*)alloc((size_t)N * 18 * 2);    // fp16 gather table, final layer

  zero_k<<<(NBKT + 255) / 256, 256, 0, stream>>>(bcnt, NBKT);
  bucket_hist_k<<<(E + HCHUNK - 1) / HCHUNK, 256, 0, stream>>>(colp, bcnt, E);
  bscan_k<<<1, 256, 0, stream>>>(bcnt, boffs, bcurs, NBKT, E);
  bucket_fill_k<<<(E + FCHUNK - 1) / FCHUNK, 256, 0, stream>>>(rowp, colp, bcurs, recs, E);
  csr_k<<<NBKT, 256, 0, stream>>>(recs, boffs, offs, adj, dis, N, E);

  int gG = (N + 127) / 128;   // 128 nodes per gemm block
  int gA = (N + 3) / 4;

  gemm64_k<100, 25><<<gG, 256, 0, stream>>>(x, W1, dis, gb, N);
  agg_f16_k<<<gA, 256, 0, stream>>>(gb, offs, adj, dis, b1, h, N);

  gemm64_k<64, 16><<<gG, 256, 0, stream>>>(h, W2, dis, gb, N);
  agg_f16_k<<<gA, 256, 0, stream>>>(gb, offs, adj, dis, b2, h, N);

  gemm64_k<64, 16><<<gG, 256, 0, stream>>>(h, W3, dis, gb, N);
  agg_f16_k<<<gA, 256, 0, stream>>>(gb, offs, adj, dis, b3, h, N);

  gemm18_k<<<gG, 256, 0, stream>>>(h, Wo, dis, g4, N);
  agg_f16o_k<<<gA, 256, 0, stream>>>(g4, offs, adj, dis, bo, out, N);
}

// Round 15
// 414.540 us; speedup vs baseline: 1.1499x; 1.0020x over previous
//
#include <hip/hip_runtime.h>
#include <hip/hip_fp16.h>

#define NODES 100000
#define NBKT 782            // ceil(100000/128) buckets of 128 cols
#define HCHUNK 8192         // edges per bucket_hist block
#define FCHUNK 4096         // edges per bucket_fill block (256 thr x 16)

typedef unsigned short u16;
typedef unsigned int u32;

__device__ __forceinline__ __half2 asH2(u32 v) {
  union { u32 u; __half2 h; } c; c.u = v; return c.h;
}

// ---------------- small utils ----------------

__global__ __launch_bounds__(256) void zero_k(int* __restrict__ p, int n) {
  int i = blockIdx.x * 256 + threadIdx.x;
  if (i < n) p[i] = 0;
}

// ---------------- bucket build ----------------

__global__ __launch_bounds__(256) void bucket_hist_k(const int* __restrict__ col,
                                                     int* __restrict__ bcnt, int E) {
  __shared__ int h[NBKT];
  int t = threadIdx.x;
  for (int i = t; i < NBKT; i += 256) h[i] = 0;
  __syncthreads();
  int base = blockIdx.x * HCHUNK;
#pragma unroll 4
  for (int j = 0; j < HCHUNK / 256; ++j) {
    int i = base + j * 256 + t;
    if (i < E) atomicAdd(&h[col[i] >> 7], 1);
  }
  __syncthreads();
  for (int i = t; i < NBKT; i += 256) {
    int c = h[i];
    if (c) atomicAdd(&bcnt[i], c);
  }
}

__global__ __launch_bounds__(256) void bscan_k(const int* __restrict__ bcnt,
                                               int* __restrict__ boffs,
                                               int* __restrict__ bcurs, int nb, int E) {
  __shared__ int lds[256];
  int t = threadIdx.x;
  int base = t * 4;
  int v[4];
#pragma unroll
  for (int j = 0; j < 4; ++j) v[j] = (base + j < nb) ? bcnt[base + j] : 0;
  int s = v[0] + v[1] + v[2] + v[3];
  lds[t] = s;
  __syncthreads();
  for (int off = 1; off < 256; off <<= 1) {
    int y = (t >= off) ? lds[t - off] : 0;
    __syncthreads();
    lds[t] += y;
    __syncthreads();
  }
  int excl = lds[t] - s;
#pragma unroll
  for (int j = 0; j < 4; ++j) {
    int i = base + j;
    if (i < nb) { boffs[i] = excl; bcurs[i] = excl; }
    excl += v[j];
  }
  if (t == 255) boffs[nb] = E;
}

// scatter packed records (colLow<<17 | row) into bucket regions.
__global__ __launch_bounds__(256) void bucket_fill_k(const int* __restrict__ row,
                                                     const int* __restrict__ col,
                                                     int* __restrict__ bcurs,
                                                     u32* __restrict__ recs, int E) {
  __shared__ int lcnt[NBKT];
  __shared__ int lbase[NBKT];
  int t = threadIdx.x;
  int base = blockIdx.x * FCHUNK;
  for (int i = t; i < NBKT; i += 256) lcnt[i] = 0;
  __syncthreads();
  u32 rec[FCHUNK / 256];
  u32 meta[FCHUNK / 256];
#pragma unroll
  for (int j = 0; j < FCHUNK / 256; ++j) {
    int i = base + j * 256 + t;
    if (i < E) {
      int r = row[i], c = col[i];
      int b = c >> 7;
      rec[j] = (u32)r | ((u32)(c & 127) << 17);
      int lr = atomicAdd(&lcnt[b], 1);
      meta[j] = (u32)lr | ((u32)b << 16);
    } else {
      meta[j] = 0xFFFFFFFFu;
    }
  }
  __syncthreads();
  for (int i = t; i < NBKT; i += 256) {
    int c = lcnt[i];
    lbase[i] = c ? atomicAdd(&bcurs[i], c) : 0;
  }
  __syncthreads();
#pragma unroll
  for (int j = 0; j < FCHUNK / 256; ++j) {
    if (meta[j] != 0xFFFFFFFFu) {
      int b = meta[j] >> 16;
      int lr = meta[j] & 0xFFFF;
      recs[lbase[b] + lr] = rec[j];
    }
  }
}

// records (bucketed by col) -> per-node CSR (offs, adj) + dis. One block per bucket.
__global__ __launch_bounds__(256) void csr_k(const u32* __restrict__ recs,
                                             const int* __restrict__ boffs,
                                             int* __restrict__ offs, int* __restrict__ adj,
                                             float* __restrict__ dis, int N, int E) {
  __shared__ int cnt[128];
  __shared__ int sa[128], sb[128];
  __shared__ int cur[128];
  int b = blockIdx.x, t = threadIdx.x;
  if (t < 128) cnt[t] = 0;
  __syncthreads();
  int s = boffs[b], e = boffs[b + 1];
  for (int i = s + t; i < e; i += 256) atomicAdd(&cnt[recs[i] >> 17], 1);
  __syncthreads();
  if (t < 128) sa[t] = cnt[t];
  __syncthreads();
#pragma unroll
  for (int off = 1; off < 128; off <<= 1) {
    if (t < 128) sb[t] = sa[t] + ((t >= off) ? sa[t - off] : 0);
    __syncthreads();
    if (t < 128) sa[t] = sb[t];
    __syncthreads();
  }
  if (t < 128) {
    int c = b * 128 + t;
    if (c < N) {
      int excl = sa[t] - cnt[t];
      offs[c] = s + excl;
      cur[t] = s + excl;
      dis[c] = rsqrtf((float)(cnt[t] + 1));  // +1 self loop
    }
  }
  if (b == 0 && t == 0) offs[N] = E;
  __syncthreads();
  for (int i = s + t; i < e; i += 256) {
    u32 r = recs[i];
    int p = atomicAdd(&cur[r >> 17], 1);
    adj[p] = (int)(r & 0x1FFFF);
  }
}

// ---------------- GEMM (NOUT=64): G[node,:] = (X[node,:] @ W) * dis[node], fp16 out ----------------
template <int K, int NK>
__global__ __launch_bounds__(256, 2) void gemm64_k(const float* __restrict__ X,
                                                   const float* __restrict__ W,
                                                   const float* __restrict__ dis,
                                                   u16* __restrict__ G, int n) {
  static_assert(K == NK * 4, "NT=4");
  __shared__ float ws[K * 64];
  int t = threadIdx.x;
  for (int i = t; i < K * 64; i += 256) ws[i] = W[i];
  __syncthreads();
  int q = t & 3, g = t >> 2;
  int b0 = blockIdx.x * 128;
  int n0 = b0 + g, n1 = b0 + 64 + g;
  int c0 = (n0 < n) ? n0 : 0, c1 = (n1 < n) ? n1 : 0;
  float xv0[NK], xv1[NK];
  const float* p0 = X + (size_t)c0 * K + q * NK;
  const float* p1 = X + (size_t)c1 * K + q * NK;
  if constexpr (NK % 4 == 0) {
#pragma unroll
    for (int i = 0; i < NK / 4; ++i) {
      *(float4*)&xv0[4 * i] = *(const float4*)(p0 + 4 * i);
      *(float4*)&xv1[4 * i] = *(const float4*)(p1 + 4 * i);
    }
  } else {
#pragma unroll
    for (int i = 0; i < NK; ++i) { xv0[i] = p0[i]; xv1[i] = p1[i]; }
  }
  float acc0[16], acc1[16];
#pragma unroll
  for (int j = 0; j < 16; ++j) { acc0[j] = 0.f; acc1[j] = 0.f; }
  for (int qq = 0; qq < 4; ++qq) {
    const float* wbase = ws + (size_t)qq * NK * 64 + q * 16;
#pragma unroll
    for (int i = 0; i < NK; ++i) {
      float a0 = __shfl(xv0[i], qq, 4);
      float a1 = __shfl(xv1[i], qq, 4);
      const float* wr = wbase + i * 64;
#pragma unroll
      for (int j = 0; j < 16; ++j) {
        float w = wr[j];
        acc0[j] = fmaf(a0, w, acc0[j]);
        acc1[j] = fmaf(a1, w, acc1[j]);
      }
    }
  }
  uint4* G4 = (uint4*)G;
  {
    if (n0 < n) {
      float sc = dis[n0];
      u32 os[8];
#pragma unroll
      for (int j = 0; j < 8; ++j) {
        u16 lo = __half_as_ushort(__float2half(acc0[2 * j] * sc));
        u16 hi = __half_as_ushort(__float2half(acc0[2 * j + 1] * sc));
        os[j] = (u32)lo | ((u32)hi << 16);
      }
      size_t rb = (size_t)n0 * 8 + q * 2;
      G4[rb]     = make_uint4(os[0], os[1], os[2], os[3]);
      G4[rb + 1] = make_uint4(os[4], os[5], os[6], os[7]);
    }
    if (n1 < n) {
      float sc = dis[n1];
      u32 os[8];
#pragma unroll
      for (int j = 0; j < 8; ++j) {
        u16 lo = __half_as_ushort(__float2half(acc1[2 * j] * sc));
        u16 hi = __half_as_ushort(__float2half(acc1[2 * j + 1] * sc));
        os[j] = (u32)lo | ((u32)hi << 16);
      }
      size_t rb = (size_t)n1 * 8 + q * 2;
      G4[rb]     = make_uint4(os[0], os[1], os[2], os[3]);
      G4[rb + 1] = make_uint4(os[4], os[5], os[6], os[7]);
    }
  }
}

// ---------------- GEMM (final, NOUT=18, fp16 out): 2 threads/node, outs split 10/8 ----------------
__global__ __launch_bounds__(256, 2) void gemm18_k(const float* __restrict__ X,  // K=64
                                                   const float* __restrict__ W,
                                                   const float* __restrict__ dis,
                                                   u16* __restrict__ G, int n) {
  __shared__ float ws[64 * 18];
  int t = threadIdx.x;
  for (int i = t; i < 64 * 18; i += 256) ws[i] = W[i];
  __syncthreads();
  int q = t & 1, g = t >> 1;
  int b0 = blockIdx.x * 128;
  int node = b0 + g;
  int cn = (node < n) ? node : 0;
  float xv[32];
  const float* p = X + (size_t)cn * 64 + q * 32;
#pragma unroll
  for (int i = 0; i < 8; ++i) *(float4*)&xv[4 * i] = *(const float4*)(p + 4 * i);
  int cnt = q ? 8 : 10;
  float acc[10];
#pragma unroll
  for (int j = 0; j < 10; ++j) acc[j] = 0.f;
  for (int qq = 0; qq < 2; ++qq) {
    const float* wbase = ws + (size_t)qq * 32 * 18 + q * 10;
#pragma unroll
    for (int i = 0; i < 32; ++i) {
      float a = __shfl(xv[i], qq, 2);
      const float* wr = wbase + i * 18;
#pragma unroll
      for (int j = 0; j < 10; ++j)
        if (j < cnt) acc[j] = fmaf(a, wr[j], acc[j]);
    }
  }
  if (node >= n) return;
  float sc = dis[node];
  u32* G32 = (u32*)G;
  if (q == 0) {
    u32 os[5];
#pragma unroll
    for (int j = 0; j < 5; ++j) {
      u16 lo = __half_as_ushort(__float2half(acc[2 * j] * sc));
      u16 hi = __half_as_ushort(__float2half(acc[2 * j + 1] * sc));
      os[j] = (u32)lo | ((u32)hi << 16);
    }
#pragma unroll
    for (int j = 0; j < 5; ++j) G32[(size_t)node * 9 + j] = os[j];
  } else {
    u32 os[4];
#pragma unroll
    for (int j = 0; j < 4; ++j) {
      u16 lo = __half_as_ushort(__float2half(acc[2 * j] * sc));
      u16 hi = __half_as_ushort(__float2half(acc[2 * j + 1] * sc));
      os[j] = (u32)lo | ((u32)hi << 16);
    }
#pragma unroll
    for (int j = 0; j < 4; ++j) G32[(size_t)node * 9 + 5 + j] = os[j];
  }
}

// ---------------- aggregation (hidden, fp16 table): 2 edges/wave-gather ----------------
// Ladder: 32 (16 gathers in flight) -> 16 (8) -> 8 (4) -> 4 (2) -> 2 -> 1.
__global__ __launch_bounds__(256) void agg_f16_k(const u16* __restrict__ g,
                                                 const int* __restrict__ offs,
                                                 const int* __restrict__ adj,
                                                 const float* __restrict__ dis,
                                                 const float* __restrict__ bias,
                                                 float* __restrict__ out, int n) {
  int node = blockIdx.x * 4 + (threadIdx.x >> 6);
  int lane = threadIdx.x & 63;
  int half = lane >> 5, fl = lane & 31;
  if (node >= n) return;
  const u32* g32 = (const u32*)g;
  float acc0 = 0.f, acc1 = 0.f;
  int s = offs[node], e = offs[node + 1];
  int i = s;
  for (; i + 32 <= e; i += 32) {  // 16 gathers in flight per lane
    int r0 = adj[i + half],      r1 = adj[i + 2 + half];
    int r2 = adj[i + 4 + half],  r3 = adj[i + 6 + half];
    int r4 = adj[i + 8 + half],  r5 = adj[i + 10 + half];
    int r6 = adj[i + 12 + half], r7 = adj[i + 14 + half];
    int r8 = adj[i + 16 + half], r9 = adj[i + 18 + half];
    int rA = adj[i + 20 + half], rB = adj[i + 22 + half];
    int rC = adj[i + 24 + half], rD = adj[i + 26 + half];
    int rE = adj[i + 28 + half], rF = adj[i + 30 + half];
    u32 v0 = g32[(r0 << 5) + fl], v1 = g32[(r1 << 5) + fl];
    u32 v2 = g32[(r2 << 5) + fl], v3 = g32[(r3 << 5) + fl];
    u32 v4 = g32[(r4 << 5) + fl], v5 = g32[(r5 << 5) + fl];
    u32 v6 = g32[(r6 << 5) + fl], v7 = g32[(r7 << 5) + fl];
    u32 v8 = g32[(r8 << 5) + fl], v9 = g32[(r9 << 5) + fl];
    u32 vA = g32[(rA << 5) + fl], vB = g32[(rB << 5) + fl];
    u32 vC = g32[(rC << 5) + fl], vD = g32[(rD << 5) + fl];
    u32 vE = g32[(rE << 5) + fl], vF = g32[(rF << 5) + fl];
    __half2 sA = __hadd2(__hadd2(asH2(v0), asH2(v1)), __hadd2(asH2(v2), asH2(v3)));
    __half2 sB = __hadd2(__hadd2(asH2(v4), asH2(v5)), __hadd2(asH2(v6), asH2(v7)));
    float2 f1 = __half22float2(__hadd2(sA, sB));
    __half2 sC = __hadd2(__hadd2(asH2(v8), asH2(v9)), __hadd2(asH2(vA), asH2(vB)));
    __half2 sD = __hadd2(__hadd2(asH2(vC), asH2(vD)), __hadd2(asH2(vE), asH2(vF)));
    float2 f2 = __half22float2(__hadd2(sC, sD));
    acc0 += f1.x + f2.x;
    acc1 += f1.y + f2.y;
  }
  if (i + 16 <= e) {  // 8 gathers in flight
    int r0 = adj[i + half],      r1 = adj[i + 2 + half];
    int r2 = adj[i + 4 + half],  r3 = adj[i + 6 + half];
    int r4 = adj[i + 8 + half],  r5 = adj[i + 10 + half];
    int r6 = adj[i + 12 + half], r7 = adj[i + 14 + half];
    u32 v0 = g32[(r0 << 5) + fl], v1 = g32[(r1 << 5) + fl];
    u32 v2 = g32[(r2 << 5) + fl], v3 = g32[(r3 << 5) + fl];
    u32 v4 = g32[(r4 << 5) + fl], v5 = g32[(r5 << 5) + fl];
    u32 v6 = g32[(r6 << 5) + fl], v7 = g32[(r7 << 5) + fl];
    __half2 sA = __hadd2(__hadd2(asH2(v0), asH2(v1)), __hadd2(asH2(v2), asH2(v3)));
    __half2 sB = __hadd2(__hadd2(asH2(v4), asH2(v5)), __hadd2(asH2(v6), asH2(v7)));
    float2 f = __half22float2(__hadd2(sA, sB));
    acc0 += f.x;
    acc1 += f.y;
    i += 16;
  }
  if (i + 8 <= e) {  // 4 gathers in flight
    int r0 = adj[i + half];
    int r1 = adj[i + 2 + half];
    int r2 = adj[i + 4 + half];
    int r3 = adj[i + 6 + half];
    u32 v0 = g32[(r0 << 5) + fl];
    u32 v1 = g32[(r1 << 5) + fl];
    u32 v2 = g32[(r2 << 5) + fl];
    u32 v3 = g32[(r3 << 5) + fl];
    float2 f = __half22float2(__hadd2(__hadd2(asH2(v0), asH2(v1)),
                                      __hadd2(asH2(v2), asH2(v3))));
    acc0 += f.x;
    acc1 += f.y;
    i += 8;
  }
  if (i + 4 <= e) {  // 2 gathers in flight
    int r0 = adj[i + half];
    int r1 = adj[i + 2 + half];
    u32 v0 = g32[(r0 << 5) + fl];
    u32 v1 = g32[(r1 << 5) + fl];
    float2 f = __half22float2(__hadd2(asH2(v0), asH2(v1)));
    acc0 += f.x;
    acc1 += f.y;
    i += 4;
  }
  if (i + 2 <= e) {
    int r = adj[i + half];
    float2 f = __half22float2(asH2(g32[(r << 5) + fl]));
    acc0 += f.x;
    acc1 += f.y;
    i += 2;
  }
  if (i < e) {  // odd tail edge: only half 0 counts it
    int r = adj[i];
    float2 f = __half22float2(asH2(g32[(r << 5) + fl]));
    if (half == 0) { acc0 += f.x; acc1 += f.y; }
  }
  acc0 += __shfl_xor(acc0, 32, 64);
  acc1 += __shfl_xor(acc1, 32, 64);
  float2 fs = __half22float2(asH2(g32[(node << 5) + fl]));  // self loop (pre-scaled)
  acc0 += fs.x;
  acc1 += fs.y;
  float d = dis[node];
  float o0 = fmaxf(fmaf(d, acc0, bias[2 * fl]), 0.f);
  float o1 = fmaxf(fmaf(d, acc1, bias[2 * fl + 1]), 0.f);
  if (half == 0) {
    float2 st = {o0, o1};
    *(float2*)(out + node * 64 + 2 * fl) = st;
  }
}

// ---------------- aggregation (final, 18-wide fp16 table): 7 edges per wave-gather ----------------
// 9 lanes per edge (each lane loads u32 = 2 fp16 feats); 63/64 lanes active; 252B/instr.
// Ladder: 28 (4 gathers in flight) -> 14 (2) -> 7 (1) -> masked tail (1..6).
// Cross-group reduce: masked folds +36, +18, +9 (7 -> 4 -> 2 -> 1 groups).
__global__ __launch_bounds__(256) void agg_f16o_k(const u16* __restrict__ g,
                                                  const int* __restrict__ offs,
                                                  const int* __restrict__ adj,
                                                  const float* __restrict__ dis,
                                                  const float* __restrict__ bias,
                                                  float* __restrict__ out, int n) {
  int node = blockIdx.x * 4 + (threadIdx.x >> 6);
  int lane = threadIdx.x & 63;
  int e7 = lane / 9;           // edge-group 0..6; lane 63 -> 7 (idle)
  int f2 = lane - e7 * 9;      // u32 index within row (feats 2*f2, 2*f2+1)
  if (node >= n) return;
  const u32* g32 = (const u32*)g;  // row = 9 u32 (18 fp16)
  bool act = e7 < 7;
  float acc0 = 0.f, acc1 = 0.f;
  int s = offs[node], e = offs[node + 1];
  if (act) {
    int i = s;
    for (; i + 28 <= e; i += 28) {  // 4 gathers in flight
      int r0 = adj[i + e7];
      int r1 = adj[i + 7 + e7];
      int r2 = adj[i + 14 + e7];
      int r3 = adj[i + 21 + e7];
      u32 v0 = g32[r0 * 9 + f2];
      u32 v1 = g32[r1 * 9 + f2];
      u32 v2 = g32[r2 * 9 + f2];
      u32 v3 = g32[r3 * 9 + f2];
      float2 f = __half22float2(__hadd2(__hadd2(asH2(v0), asH2(v1)),
                                        __hadd2(asH2(v2), asH2(v3))));
      acc0 += f.x;
      acc1 += f.y;
    }
    if (i + 14 <= e) {  // 2 in flight
      int r0 = adj[i + e7];
      int r1 = adj[i + 7 + e7];
      u32 v0 = g32[r0 * 9 + f2];
      u32 v1 = g32[r1 * 9 + f2];
      float2 f = __half22float2(__hadd2(asH2(v0), asH2(v1)));
      acc0 += f.x;
      acc1 += f.y;
      i += 14;
    }
    if (i + 7 <= e) {
      int r = adj[i + e7];
      float2 f = __half22float2(asH2(g32[r * 9 + f2]));
      acc0 += f.x;
      acc1 += f.y;
      i += 7;
    }
    if (i < e) {  // tail m in 1..6; group e7 contributes iff e7 < m
      int m = e - i;
      int idx = (e7 < m) ? (i + e7) : i;
      float2 f = __half22float2(asH2(g32[adj[idx] * 9 + f2]));
      if (e7 < m) { acc0 += f.x; acc1 += f.y; }
    }
  }
  // fold 7 groups -> 1 (inactive lane 63 holds 0): +36 (g<3), +18 (g<2), +9 (g<1)
  float t0, t1;
  t0 = __shfl(acc0, lane + 36, 64); t1 = __shfl(acc1, lane + 36, 64);
  if (e7 < 3) { acc0 += t0; acc1 += t1; }
  t0 = __shfl(acc0, lane + 18, 64); t1 = __shfl(acc1, lane + 18, 64);
  if (e7 < 2) { acc0 += t0; acc1 += t1; }
  t0 = __shfl(acc0, lane + 9, 64);  t1 = __shfl(acc1, lane + 9, 64);
  if (e7 < 1) { acc0 += t0; acc1 += t1; }
  if (lane < 9) {
    float2 fs = __half22float2(asH2(g32[node * 9 + lane]));  // self loop
    acc0 += fs.x;
    acc1 += fs.y;
    float d = dis[node];
    float2 o;
    o.x = fmaf(d, acc0, bias[2 * lane]);
    o.y = fmaf(d, acc1, bias[2 * lane + 1]);
    *(float2*)(out + node * 18 + 2 * lane) = o;  // 72B rows -> 8B aligned
  }
}

// ---------------- launch ----------------

extern "C" void kernel_launch(void* const* d_in, const int* in_sizes, int n_in,
                              void* d_out, int out_size, void* d_ws, size_t ws_size,
                              hipStream_t stream) {
  const float* x  = (const float*)d_in[0];
  const int*   ei = (const int*)d_in[1];
  const float* W1 = (const float*)d_in[2];
  const float* b1 = (const float*)d_in[3];
  const float* W2 = (const float*)d_in[4];
  const float* b2 = (const float*)d_in[5];
  const float* W3 = (const float*)d_in[6];
  const float* b3 = (const float*)d_in[7];
  const float* Wo = (const float*)d_in[8];
  const float* bo = (const float*)d_in[9];
  float* out = (float*)d_out;

  const int N = NODES;
  const int E = in_sizes[1] / 2;
  const int* rowp = ei;
  const int* colp = ei + E;

  char* p = (char*)d_ws;
  auto alloc = [&](size_t bytes) {
    void* r = (void*)p;
    p += (bytes + 255) & ~(size_t)255;
    return r;
  };
  int*   bcnt  = (int*)alloc((size_t)NBKT * 4);
  int*   bcurs = (int*)alloc((size_t)NBKT * 4);
  int*   boffs = (int*)alloc((size_t)(NBKT + 1) * 4);
  float* dis   = (float*)alloc((size_t)N * 4);
  int*   offs  = (int*)alloc((size_t)(N + 1) * 4);
  int*   adj   = (int*)alloc((size_t)E * 4);
  // recs (E*4 = 12.8MB) dead after csr_k; alias with fp16 gather table (N*64*2 = 12.8MB)
  u32*   recs  = (u32*)alloc((size_t)N * 64 * 2);
  u16*   gb    = (u16*)recs;
  float* h     = (float*)alloc((size_t)N * 64 * 4);   // fp32 hidden activations
  u16*   g4    = (u16*)alloc((size_t)N * 18 * 2);    // fp16 gather table, final layer

  zero_k<<<(NBKT + 255) / 256, 256, 0, stream>>>(bcnt, NBKT);
  bucket_hist_k<<<(E + HCHUNK - 1) / HCHUNK, 256, 0, stream>>>(colp, bcnt, E);
  bscan_k<<<1, 256, 0, stream>>>(bcnt, boffs, bcurs, NBKT, E);
  bucket_fill_k<<<(E + FCHUNK - 1) / FCHUNK, 256, 0, stream>>>(rowp, colp, bcurs, recs, E);
  csr_k<<<NBKT, 256, 0, stream>>>(recs, boffs, offs, adj, dis, N, E);

  int gG = (N + 127) / 128;   // 128 nodes per gemm block
  int gA = (N + 3) / 4;

  gemm64_k<100, 25><<<gG, 256, 0, stream>>>(x, W1, dis, gb, N);
  agg_f16_k<<<gA, 256, 0, stream>>>(gb, offs, adj, dis, b1, h, N);

  gemm64_k<64, 16><<<gG, 256, 0, stream>>>(h, W2, dis, gb, N);
  agg_f16_k<<<gA, 256, 0, stream>>>(gb, offs, adj, dis, b2, h, N);

  gemm64_k<64, 16><<<gG, 256, 0, stream>>>(h, W3, dis, gb, N);
  agg_f16_k<<<gA, 256, 0, stream>>>(gb, offs, adj, dis, b3, h, N);

  gemm18_k<<<gG, 256, 0, stream>>>(h, Wo, dis, g4, N);
  agg_f16o_k<<<gA, 256, 0, stream>>>(g4, offs, adj, dis, bo, out, N);
}